// Round 16
// baseline (136.035 us; speedup 1.0000x reference)
//
#include <hip/hip_runtime.h>
#include <math.h>

// Problem constants: B=2, T=2048, C=1024, H=16, D=64
constexpr int Bb = 2;
constexpr int Tt = 2048;
constexpr int Cc = 1024;
constexpr int Hh = 16;
constexpr int M_ROWS = Bb * Tt;          // 4096
constexpr float EPSV = 1e-5f;

typedef __attribute__((ext_vector_type(4))) float f32x4;
typedef __attribute__((ext_vector_type(8))) __bf16 bf16x8;
using u16 = unsigned short;

union Frag8 {
    u16 u[8];
    unsigned int ui[4];
    uint4 v;
    bf16x8 b;
};

// fp32 -> bf16 round-to-nearest-even
__device__ __forceinline__ u16 f2bf(float f) {
    union { float f; unsigned int u; } c;
    c.f = f;
    unsigned int r = (c.u + 0x7fffu + ((c.u >> 16) & 1u)) >> 16;
    return (u16)r;
}
__device__ __forceinline__ float bf2f(u16 u) {
    union { unsigned int i; float f; } c;
    c.i = ((unsigned int)u) << 16;
    return c.f;
}

// async global->LDS, 16 B per lane; LDS dest = wave-uniform base + lane*16
__device__ __forceinline__ void gload_lds16(const void* g, void* l) {
    __builtin_amdgcn_global_load_lds(
        (__attribute__((address_space(1))) void*)const_cast<void*>(g),
        (__attribute__((address_space(3))) void*)l, 16, 0, 0);
}

// ---------------------------------------------------------------------------
// RoPE tables, TRANSPOSED [32][T]: cos2[j*T + t] = cos(t * 10000^(-j/32))
// (float4-loadable by the GEMM epilogue: consecutive t for fixed j)
// ---------------------------------------------------------------------------
__global__ __launch_bounds__(256) void rope_tables_k(float* __restrict__ cos2,
                                                     float* __restrict__ sin2) {
    int lin = blockIdx.x * 256 + threadIdx.x;   // 65536 = 32*2048
    int j = lin >> 11;
    int t = lin & 2047;
    float inv = exp2f(-(float)j * (log2f(10000.0f) / 32.0f));
    float a = (float)t * inv;
    cos2[lin] = cosf(a);
    sin2[lin] = sinf(a);
}

// ---------------------------------------------------------------------------
// fp32 -> bf16 array convert (for weights), 4 elems/thread
// ---------------------------------------------------------------------------
__global__ __launch_bounds__(256) void f2bf_arr_k(const float* __restrict__ in,
                                                  u16* __restrict__ out) {
    int i = (blockIdx.x * 256 + threadIdx.x) * 4;
    float4 v = *(const float4*)&in[i];
    ushort4 o;
    o.x = f2bf(v.x); o.y = f2bf(v.y); o.z = f2bf(v.z); o.w = f2bf(v.w);
    *(ushort4*)&out[i] = o;
}

// ---------------------------------------------------------------------------
// RMSNorm: one block per row of C=1024; 256 threads x float4 -> bf16 out
// ---------------------------------------------------------------------------
__global__ __launch_bounds__(256) void rmsnorm_k(const float* __restrict__ x,
                                                 const float* __restrict__ w,
                                                 u16* __restrict__ xn) {
    int row = blockIdx.x;
    int tid = threadIdx.x;
    const float* xr = x + (size_t)row * Cc;
    float4 v = *(const float4*)&xr[tid * 4];
    float ss = v.x * v.x + v.y * v.y + v.z * v.z + v.w * v.w;
    #pragma unroll
    for (int off = 32; off > 0; off >>= 1) ss += __shfl_down(ss, off);
    __shared__ float ws_[4];
    if ((tid & 63) == 0) ws_[tid >> 6] = ss;
    __syncthreads();
    float tot = ws_[0] + ws_[1] + ws_[2] + ws_[3];
    float r = rsqrtf(tot * (1.0f / (float)Cc) + EPSV);
    float4 wv = *(const float4*)&w[tid * 4];
    ushort4 o;
    o.x = f2bf(v.x * r * wv.x);
    o.y = f2bf(v.y * r * wv.y);
    o.z = f2bf(v.z * r * wv.z);
    o.w = f2bf(v.w * r * wv.w);
    *(ushort4*)&xn[(size_t)row * Cc + tid * 4] = o;
}

// ---------------------------------------------------------------------------
// bf16 MFMA GEMM, 128x128 tile, BK=64, 4 waves (2x2), global_load_lds with
// source-chunk XOR swizzle (rule #21), 1D grid with XCD swizzle (T1,
// column-major decode: each XCD keeps a W-panel L2-resident).
// MODE 0: O[M][N] = A*W^T + bias, fp32 out (O-projection).
// MODE 1: QKV fused epilogue — bias + RoPE (Q scaled by 0.125*log2e) +
//         head-major pack: Qb/Kb [bh][t][64] bf16, Vt [bh][64][T] bf16 with
//         pi^-1 slot permutation (slot bits {k5,k3,k2,k4,k1,k0}).
// ---------------------------------------------------------------------------
template<int MODE>
__global__ __launch_bounds__(256) void gemm_mfma_k(const u16* __restrict__ A,
                                                   const u16* __restrict__ W,
                                                   const float* __restrict__ bias,
                                                   float* __restrict__ Ov,
                                                   int M, int N, int K,
                                                   const float* __restrict__ cos2,
                                                   const float* __restrict__ sin2,
                                                   u16* __restrict__ Qb,
                                                   u16* __restrict__ Kb,
                                                   u16* __restrict__ Vt) {
    __shared__ __align__(16) u16 As[128 * 64];   // 16 KB
    __shared__ __align__(16) u16 Bs[128 * 64];   // 16 KB

    // ---- XCD-swizzled 1D grid decode (nwg % 8 == 0) ----
    const int nwg = gridDim.x;
    const int lin = blockIdx.x;
    const int swz = (lin & 7) * (nwg >> 3) + (lin >> 3);
    const int mblk = M >> 7;
    const int bx = swz / mblk, by = swz % mblk;
    const int m0 = by * 128, n0 = bx * 128;

    const int tid = threadIdx.x;
    const int w = tid >> 6;
    const int l = tid & 63;
    const int wr = w >> 1;
    const int wc = w & 1;
    const int q = l & 15;
    const int g = l >> 4;

    const int srow_in = l >> 3;
    const int p_chunk = l & 7;

    f32x4 acc[4][4];
    #pragma unroll
    for (int i = 0; i < 4; ++i)
        #pragma unroll
        for (int j = 0; j < 4; ++j)
            acc[i][j] = (f32x4){0.f, 0.f, 0.f, 0.f};

    const int nkt = K >> 6;
    for (int kt = 0; kt < nkt; ++kt) {
        const int k0 = kt << 6;
        __syncthreads();
        #pragma unroll
        for (int s = 0; s < 4; ++s) {
            int blk = s * 4 + w;
            int r = blk * 8 + srow_in;
            int c = p_chunk ^ (r & 7);
            gload_lds16(A + (size_t)(m0 + r) * K + k0 + c * 8, &As[blk * 512]);
            gload_lds16(W + (size_t)(n0 + r) * K + k0 + c * 8, &Bs[blk * 512]);
        }
        __syncthreads();

        #pragma unroll
        for (int kk = 0; kk < 2; ++kk) {
            Frag8 af[4], bf[4];
            const int ca = kk * 4 + g;
            #pragma unroll
            for (int i = 0; i < 4; ++i) {
                int ra = wr * 64 + i * 16 + q;
                af[i] = *(const Frag8*)&As[ra * 64 + ((ca ^ (ra & 7)) * 8)];
                int rb = wc * 64 + i * 16 + q;
                bf[i] = *(const Frag8*)&Bs[rb * 64 + ((ca ^ (rb & 7)) * 8)];
            }
            #pragma unroll
            for (int i = 0; i < 4; ++i)
                #pragma unroll
                for (int j = 0; j < 4; ++j)
                    acc[i][j] = __builtin_amdgcn_mfma_f32_16x16x32_bf16(
                        af[i].b, bf[j].b, acc[i][j], 0, 0, 0);
        }
    }

    // ---- epilogue ----
    float bj[4];
    #pragma unroll
    for (int j = 0; j < 4; ++j) bj[j] = bias[n0 + wc * 64 + j * 16 + q];

    if (MODE == 0) {
        #pragma unroll
        for (int i = 0; i < 4; ++i) {
            int row = m0 + wr * 64 + i * 16 + g * 4;
            #pragma unroll
            for (int j = 0; j < 4; ++j) {
                int col = n0 + wc * 64 + j * 16 + q;
                #pragma unroll
                for (int r2 = 0; r2 < 4; ++r2)
                    Ov[(size_t)(row + r2) * N + col] = acc[i][j][r2] + bj[j];
            }
        }
    } else {
        constexpr float QSC = 0.125f * 1.44269504089f;  // 1/sqrt(D)*log2(e)
        const int ncb = n0 + wc * 64;       // 64-aligned -> single (plane, head)
        const int plane = ncb >> 10;        // 0=q, 1=k, 2=v
        const int hh = (ncb & 1023) >> 6;
        #pragma unroll
        for (int i = 0; i < 4; ++i) {
            int row0 = m0 + wr * 64 + i * 16 + g * 4;   // multiple of 4
            int bb_ = row0 >> 11;
            int t0 = row0 & 2047;
            int bh2 = bb_ * Hh + hh;
            if (plane == 2) {
                // V: no rope; transposed + pi^-1 slot; 4 consecutive t pack
                int u0 = t0 & 63;
                int slot0 = (u0 & 32) | ((u0 & 8) << 1) | ((u0 & 4) << 1) | ((u0 & 16) >> 2);
                int tbase = (t0 & ~63) + slot0;
                #pragma unroll
                for (int j = 0; j < 4; ++j) {
                    int d = j * 16 + q;
                    ushort4 o;
                    o.x = f2bf(acc[i][j][0] + bj[j]);
                    o.y = f2bf(acc[i][j][1] + bj[j]);
                    o.z = f2bf(acc[i][j][2] + bj[j]);
                    o.w = f2bf(acc[i][j][3] + bj[j]);
                    *(ushort4*)&Vt[((size_t)bh2 * 64 + d) * Tt + tbase] = o;
                }
            } else {
                // Q/K: rope pairs (j0,j2) at table row q, (j1,j3) at q+16
                float4 c0 = *(const float4*)&cos2[q * Tt + t0];
                float4 s0 = *(const float4*)&sin2[q * Tt + t0];
                float4 c1 = *(const float4*)&cos2[(q + 16) * Tt + t0];
                float4 s1 = *(const float4*)&sin2[(q + 16) * Tt + t0];
                float cc0[4] = {c0.x, c0.y, c0.z, c0.w};
                float ss0[4] = {s0.x, s0.y, s0.z, s0.w};
                float cc1[4] = {c1.x, c1.y, c1.z, c1.w};
                float ss1[4] = {s1.x, s1.y, s1.z, s1.w};
                u16* dst = (plane == 0 ? Qb : Kb) + ((size_t)bh2 * Tt + t0) * 64;
                const float scl = (plane == 0) ? QSC : 1.0f;
                #pragma unroll
                for (int r2 = 0; r2 < 4; ++r2) {
                    float v0 = acc[i][0][r2] + bj[0];
                    float v1 = acc[i][1][r2] + bj[1];
                    float v2 = acc[i][2][r2] + bj[2];
                    float v3 = acc[i][3][r2] + bj[3];
                    u16* p = dst + (size_t)r2 * 64;
                    p[q]      = f2bf((v0 * cc0[r2] - v2 * ss0[r2]) * scl);
                    p[q + 16] = f2bf((v1 * cc1[r2] - v3 * ss1[r2]) * scl);
                    p[q + 32] = f2bf((v2 * cc0[r2] + v0 * ss0[r2]) * scl);
                    p[q + 48] = f2bf((v3 * cc1[r2] + v1 * ss1[r2]) * scl);
                }
            }
        }
    }
}

// ---------------------------------------------------------------------------
// MFMA flash attention v9 (unchanged winner from R15).
// ---------------------------------------------------------------------------
__global__ __launch_bounds__(256) void attn_mfma_k(const u16* __restrict__ Qb,
                                                   const u16* __restrict__ Kb,
                                                   const u16* __restrict__ Vt,
                                                   u16* __restrict__ out) {
    const int i = blockIdx.x;           // 0..1023
    int c, bh;
    if (i < 512) { c = 31 - (i >> 5); bh = i & 31; }        // heavy first
    else         { int k = i - 512; c = k >> 5; bh = k & 31; }
    const int b = bh >> 4, h = bh & 15;

    const int t = threadIdx.x;
    const int w = t >> 6;        // wave 0..3
    const int l = t & 63;
    const int q15 = l & 15;
    const int g2 = l >> 4;

    __shared__ __align__(16) u16 Ks[2][64 * 64];   // 16 KB
    __shared__ __align__(16) u16 VTs[2][64 * 64];  // 16 KB

    Frag8 qf[2];
    {
        int qrow = c * 64 + w * 16 + q15;
        const u16* qp = Qb + ((size_t)bh * Tt + qrow) * 64;
        qf[0] = *(const Frag8*)&qp[g2 * 8];
        qf[1] = *(const Frag8*)&qp[32 + g2 * 8];
    }

    Frag8 ones;
    #pragma unroll
    for (int e = 0; e < 8; ++e) ones.u[e] = 0x3F80;   // bf16 1.0

    f32x4 acco[4];
    #pragma unroll
    for (int dg = 0; dg < 4; ++dg) acco[dg] = (f32x4){0.f, 0.f, 0.f, 0.f};
    f32x4 acc_l = (f32x4){0.f, 0.f, 0.f, 0.f};

    const int srow = l >> 3;
    const int cph = l & 7;
    const int cl = cph ^ srow;
    const u16* Kbase = Kb + (size_t)bh * Tt * 64;
    const u16* Vbase = Vt + (size_t)bh * 64 * Tt;

    #pragma unroll
    for (int iss = 0; iss < 2; ++iss) {
        int rr = w * 16 + iss * 8 + srow;
        gload_lds16(Kbase + (size_t)rr * 64 + cl * 8, &Ks[0][(w * 16 + iss * 8) * 64]);
        gload_lds16(Vbase + (size_t)rr * Tt + cl * 8, &VTs[0][(w * 16 + iss * 8) * 64]);
    }
    __syncthreads();

    int cur = 0;
    for (int j = 0; j <= c; ++j) {
        if (j < c) {
            #pragma unroll
            for (int iss = 0; iss < 2; ++iss) {
                int rr = w * 16 + iss * 8 + srow;
                gload_lds16(Kbase + (size_t)((j + 1) * 64 + rr) * 64 + cl * 8,
                            &Ks[cur ^ 1][(w * 16 + iss * 8) * 64]);
                gload_lds16(Vbase + (size_t)rr * Tt + (j + 1) * 64 + cl * 8,
                            &VTs[cur ^ 1][(w * 16 + iss * 8) * 64]);
            }
        }

        const u16* Kc = Ks[cur];
        const u16* Vc = VTs[cur];
        f32x4 sacc[4];
        __builtin_amdgcn_s_setprio(1);
        #pragma unroll
        for (int g = 0; g < 4; ++g) {
            sacc[g] = (f32x4){0.f, 0.f, 0.f, 0.f};
            int krow = g * 16 + q15;
            #pragma unroll
            for (int kk = 0; kk < 2; ++kk) {
                Frag8 kf = *(const Frag8*)&Kc[krow * 64 + (((kk * 4 + g2) ^ (krow & 7)) * 8)];
                sacc[g] = __builtin_amdgcn_mfma_f32_16x16x32_bf16(
                    kf.b, qf[kk].b, sacc[g], 0, 0, 0);
            }
        }
        __builtin_amdgcn_s_setprio(0);
        if (j == c) {
            #pragma unroll
            for (int g = 0; g < 4; ++g)
                #pragma unroll
                for (int r = 0; r < 4; ++r)
                    if (g * 16 + g2 * 4 + r > w * 16 + q15) sacc[g][r] = -1e30f;
        }

        Frag8 pa[2];
        #pragma unroll
        for (int kk = 0; kk < 2; ++kk)
            #pragma unroll
            for (int e = 0; e < 8; ++e)
                pa[kk].b[e] = (__bf16)exp2f(sacc[2 * kk + (e >> 2)][e & 3]);

        __builtin_amdgcn_s_setprio(1);
        acc_l = __builtin_amdgcn_mfma_f32_16x16x32_bf16(pa[0].b, ones.b, acc_l, 0, 0, 0);
        acc_l = __builtin_amdgcn_mfma_f32_16x16x32_bf16(pa[1].b, ones.b, acc_l, 0, 0, 0);
        #pragma unroll
        for (int dg = 0; dg < 4; ++dg) {
            int vrow = dg * 16 + q15;
            #pragma unroll
            for (int kk = 0; kk < 2; ++kk) {
                Frag8 vf = *(const Frag8*)&Vc[vrow * 64 + (((kk * 4 + g2) ^ (vrow & 7)) * 8)];
                acco[dg] = __builtin_amdgcn_mfma_f32_16x16x32_bf16(
                    pa[kk].b, vf.b, acco[dg], 0, 0, 0);
            }
        }
        __builtin_amdgcn_s_setprio(0);

        if (j < c) __syncthreads();
        cur ^= 1;
    }

    float lr[4];
    #pragma unroll
    for (int r = 0; r < 4; ++r) lr[r] = 1.f / acc_l[r];
    const int qbase = c * 64 + w * 16;
    #pragma unroll
    for (int dg = 0; dg < 4; ++dg)
        #pragma unroll
        for (int r = 0; r < 4; ++r)
            out[((size_t)(b * Tt + qbase + g2 * 4 + r)) * Cc + h * 64 + dg * 16 + q15] =
                f2bf(acco[dg][r] * lr[r]);
}

// ---------------------------------------------------------------------------
// Launch
// ---------------------------------------------------------------------------
extern "C" void kernel_launch(void* const* d_in, const int* in_sizes, int n_in,
                              void* d_out, int out_size, void* d_ws, size_t ws_size,
                              hipStream_t stream) {
    const float* x      = (const float*)d_in[0];
    const float* w_qkv  = (const float*)d_in[2];
    const float* b_qkv  = (const float*)d_in[3];
    const float* w_o    = (const float*)d_in[4];
    const float* b_o    = (const float*)d_in[5];
    const float* rms_w  = (const float*)d_in[6];
    float* out = (float*)d_out;

    char* ws = (char*)d_ws;
    u16*   xn_bf   = (u16*)ws;                                   // 8 MB [0,8)
    u16*   Kb      = (u16*)(ws + (size_t)(8 << 20));             // 8 MB [8,16)
    u16*   Vt      = (u16*)(ws + (size_t)(16 << 20));            // 8 MB [16,24)
    u16*   Qb      = (u16*)(ws + (size_t)(24 << 20));            // 8 MB [24,32)
    u16*   wqkv_bf = (u16*)(ws + (size_t)(56 << 20));            // 6 MB [56,62)
    u16*   wo_bf   = (u16*)(ws + (size_t)(62 << 20));            // 2 MB [62,64)
    float* cos2    = (float*)(ws + (size_t)(64 << 20));          // 256 KB
    float* sin2    = (float*)(ws + (size_t)(64 << 20) + (1 << 18));
    u16*   attn_bf = xn_bf;   // xn dead after QKV GEMM

    rope_tables_k<<<dim3(256), dim3(256), 0, stream>>>(cos2, sin2);
    f2bf_arr_k<<<dim3(3 * Cc * Cc / 1024), dim3(256), 0, stream>>>(w_qkv, wqkv_bf);
    f2bf_arr_k<<<dim3(Cc * Cc / 1024), dim3(256), 0, stream>>>(w_o, wo_bf);
    rmsnorm_k<<<dim3(M_ROWS), dim3(256), 0, stream>>>(x, rms_w, xn_bf);
    gemm_mfma_k<1><<<dim3((3 * Cc / 128) * (M_ROWS / 128)), dim3(256), 0, stream>>>(
        xn_bf, wqkv_bf, b_qkv, nullptr, M_ROWS, 3 * Cc, Cc,
        cos2, sin2, Qb, Kb, Vt);
    attn_mfma_k<<<dim3(1024), dim3(256), 0, stream>>>(Qb, Kb, Vt, attn_bf);
    gemm_mfma_k<0><<<dim3((Cc / 128) * (M_ROWS / 128)), dim3(256), 0, stream>>>(
        attn_bf, wo_bf, b_o, out, M_ROWS, Cc, Cc,
        nullptr, nullptr, nullptr, nullptr, nullptr);
}

// Round 17
// 131.261 us; speedup vs baseline: 1.0364x; 1.0364x over previous
//
#include <hip/hip_runtime.h>
#include <math.h>

// Problem constants: B=2, T=2048, C=1024, H=16, D=64
constexpr int Bb = 2;
constexpr int Tt = 2048;
constexpr int Cc = 1024;
constexpr int Hh = 16;
constexpr int M_ROWS = Bb * Tt;          // 4096
constexpr float EPSV = 1e-5f;

typedef __attribute__((ext_vector_type(4))) float f32x4;
typedef __attribute__((ext_vector_type(8))) __bf16 bf16x8;
using u16 = unsigned short;

union Frag8 {
    u16 u[8];
    unsigned int ui[4];
    uint4 v;
    bf16x8 b;
};

// fp32 -> bf16 round-to-nearest-even
__device__ __forceinline__ u16 f2bf(float f) {
    union { float f; unsigned int u; } c;
    c.f = f;
    unsigned int r = (c.u + 0x7fffu + ((c.u >> 16) & 1u)) >> 16;
    return (u16)r;
}
__device__ __forceinline__ float bf2f(u16 u) {
    union { unsigned int i; float f; } c;
    c.i = ((unsigned int)u) << 16;
    return c.f;
}

// async global->LDS, 16 B per lane; LDS dest = wave-uniform base + lane*16
__device__ __forceinline__ void gload_lds16(const void* g, void* l) {
    __builtin_amdgcn_global_load_lds(
        (__attribute__((address_space(1))) void*)const_cast<void*>(g),
        (__attribute__((address_space(3))) void*)l, 16, 0, 0);
}

// ---------------------------------------------------------------------------
// Prep (merged): weight bf16 converts + RoPE tables [T][32].
// Grid 4352 x 256: [0,3072) w_qkv, [3072,4096) w_o, [4096,4352) tables.
// ---------------------------------------------------------------------------
__global__ __launch_bounds__(256) void prep_k(const float* __restrict__ w_qkv,
                                              u16* __restrict__ wqkv_bf,
                                              const float* __restrict__ w_o,
                                              u16* __restrict__ wo_bf,
                                              float* __restrict__ cosT,
                                              float* __restrict__ sinT) {
    int blk = blockIdx.x;
    if (blk < 3072) {
        int i = (blk * 256 + threadIdx.x) * 4;
        float4 v = *(const float4*)&w_qkv[i];
        ushort4 o;
        o.x = f2bf(v.x); o.y = f2bf(v.y); o.z = f2bf(v.z); o.w = f2bf(v.w);
        *(ushort4*)&wqkv_bf[i] = o;
    } else if (blk < 4096) {
        int i = ((blk - 3072) * 256 + threadIdx.x) * 4;
        float4 v = *(const float4*)&w_o[i];
        ushort4 o;
        o.x = f2bf(v.x); o.y = f2bf(v.y); o.z = f2bf(v.z); o.w = f2bf(v.w);
        *(ushort4*)&wo_bf[i] = o;
    } else {
        int lin = (blk - 4096) * 256 + threadIdx.x;   // 0..65535 = t*32+j
        int tt = lin >> 5, j = lin & 31;
        float inv = exp2f(-(float)j * (log2f(10000.0f) / 32.0f));
        float a = (float)tt * inv;
        cosT[lin] = cosf(a);
        sinT[lin] = sinf(a);
    }
}

// ---------------------------------------------------------------------------
// RMSNorm: one block per row of C=1024; 256 threads x float4 -> bf16 out
// ---------------------------------------------------------------------------
__global__ __launch_bounds__(256) void rmsnorm_k(const float* __restrict__ x,
                                                 const float* __restrict__ w,
                                                 u16* __restrict__ xn) {
    int row = blockIdx.x;
    int tid = threadIdx.x;
    const float* xr = x + (size_t)row * Cc;
    float4 v = *(const float4*)&xr[tid * 4];
    float ss = v.x * v.x + v.y * v.y + v.z * v.z + v.w * v.w;
    #pragma unroll
    for (int off = 32; off > 0; off >>= 1) ss += __shfl_down(ss, off);
    __shared__ float ws_[4];
    if ((tid & 63) == 0) ws_[tid >> 6] = ss;
    __syncthreads();
    float tot = ws_[0] + ws_[1] + ws_[2] + ws_[3];
    float r = rsqrtf(tot * (1.0f / (float)Cc) + EPSV);
    float4 wv = *(const float4*)&w[tid * 4];
    ushort4 o;
    o.x = f2bf(v.x * r * wv.x);
    o.y = f2bf(v.y * r * wv.y);
    o.z = f2bf(v.z * r * wv.z);
    o.w = f2bf(v.w * r * wv.w);
    *(ushort4*)&xn[(size_t)row * Cc + tid * 4] = o;
}

// ---------------------------------------------------------------------------
// bf16 MFMA GEMM (R15 version): O = A*W^T + bias. 128x128, BK=64, 4 waves.
// 2D grid (default decode is already XCD/L2-friendly at these shapes).
// ---------------------------------------------------------------------------
template<bool BF16OUT>
__global__ __launch_bounds__(256) void gemm_mfma_k(const u16* __restrict__ A,
                                                   const u16* __restrict__ W,
                                                   const float* __restrict__ bias,
                                                   void* __restrict__ Ov,
                                                   int M, int N, int K) {
    __shared__ __align__(16) u16 As[128 * 64];   // 16 KB
    __shared__ __align__(16) u16 Bs[128 * 64];   // 16 KB

    const int tid = threadIdx.x;
    const int w = tid >> 6;
    const int l = tid & 63;
    const int wr = w >> 1;
    const int wc = w & 1;
    const int q = l & 15;
    const int g = l >> 4;

    const int m0 = blockIdx.y * 128;
    const int n0 = blockIdx.x * 128;

    const int srow_in = l >> 3;
    const int p_chunk = l & 7;

    f32x4 acc[4][4];
    #pragma unroll
    for (int i = 0; i < 4; ++i)
        #pragma unroll
        for (int j = 0; j < 4; ++j)
            acc[i][j] = (f32x4){0.f, 0.f, 0.f, 0.f};

    const int nkt = K >> 6;
    for (int kt = 0; kt < nkt; ++kt) {
        const int k0 = kt << 6;
        __syncthreads();
        #pragma unroll
        for (int s = 0; s < 4; ++s) {
            int blk = s * 4 + w;
            int r = blk * 8 + srow_in;
            int c = p_chunk ^ (r & 7);
            gload_lds16(A + (size_t)(m0 + r) * K + k0 + c * 8, &As[blk * 512]);
            gload_lds16(W + (size_t)(n0 + r) * K + k0 + c * 8, &Bs[blk * 512]);
        }
        __syncthreads();

        #pragma unroll
        for (int kk = 0; kk < 2; ++kk) {
            Frag8 af[4], bf[4];
            const int ca = kk * 4 + g;
            #pragma unroll
            for (int i = 0; i < 4; ++i) {
                int ra = wr * 64 + i * 16 + q;
                af[i] = *(const Frag8*)&As[ra * 64 + ((ca ^ (ra & 7)) * 8)];
                int rb = wc * 64 + i * 16 + q;
                bf[i] = *(const Frag8*)&Bs[rb * 64 + ((ca ^ (rb & 7)) * 8)];
            }
            #pragma unroll
            for (int i = 0; i < 4; ++i)
                #pragma unroll
                for (int j = 0; j < 4; ++j)
                    acc[i][j] = __builtin_amdgcn_mfma_f32_16x16x32_bf16(
                        af[i].b, bf[j].b, acc[i][j], 0, 0, 0);
        }
    }

    #pragma unroll
    for (int i = 0; i < 4; ++i) {
        int row = m0 + wr * 64 + i * 16 + g * 4;
        #pragma unroll
        for (int j = 0; j < 4; ++j) {
            int col = n0 + wc * 64 + j * 16 + q;
            float bb = bias[col];
            #pragma unroll
            for (int r2 = 0; r2 < 4; ++r2) {
                float val = acc[i][j][r2] + bb;
                if (BF16OUT)
                    ((u16*)Ov)[(size_t)(row + r2) * N + col] = f2bf(val);
                else
                    ((float*)Ov)[(size_t)(row + r2) * N + col] = val;
            }
        }
    }
}

// ---------------------------------------------------------------------------
// RoPE + repack (R15 version): qkv_bf16 [b,t,3,h,64] -> Qb/Kb [b,h,t,64]
// (Q pre-scaled by 0.125*log2e), Vt [b,h,64,T] with pi key permutation.
// ---------------------------------------------------------------------------
__global__ __launch_bounds__(256) void rope_pack_k(const u16* __restrict__ qkv,
                                                   const float* __restrict__ cosT,
                                                   const float* __restrict__ sinT,
                                                   u16* __restrict__ Qb,
                                                   u16* __restrict__ Kb,
                                                   u16* __restrict__ Vt) {
    const int t0 = blockIdx.x * 64;
    const int h = blockIdx.y, b = blockIdx.z;
    const int t = threadIdx.x;
    const int bh = b * Hh + h;
    __shared__ u16 Vs[64 * 64];
    constexpr float QSC = 0.125f * 1.44269504089f;   // 1/sqrt(D) * log2(e)

    {
        int row = t >> 2, d16 = (t & 3) * 16;
        const u16* vp = qkv + (size_t)(b * Tt + t0 + row) * 3072 + 2048 + h * 64 + d16;
        *(uint4*)&Vs[row * 64 + d16]     = *(const uint4*)vp;
        *(uint4*)&Vs[row * 64 + d16 + 8] = *(const uint4*)(vp + 8);
    }

    {
        int row = t >> 2, d0 = (t & 3) * 8;
        size_t rb = (size_t)(b * Tt + t0 + row) * 3072 + h * 64;
        const u16* qp = qkv + rb;
        const u16* kp = qkv + rb + 1024;
        Frag8 qlo, qhi, klo, khi;
        qlo.v = *(const uint4*)&qp[d0];
        qhi.v = *(const uint4*)&qp[d0 + 32];
        klo.v = *(const uint4*)&kp[d0];
        khi.v = *(const uint4*)&kp[d0 + 32];
        const float* cp = &cosT[(t0 + row) * 32 + d0];
        const float* sp = &sinT[(t0 + row) * 32 + d0];
        float4 c0 = *(const float4*)cp, c1 = *(const float4*)(cp + 4);
        float4 s0 = *(const float4*)sp, s1 = *(const float4*)(sp + 4);
        float cc[8] = {c0.x, c0.y, c0.z, c0.w, c1.x, c1.y, c1.z, c1.w};
        float ss[8] = {s0.x, s0.y, s0.z, s0.w, s1.x, s1.y, s1.z, s1.w};
        Frag8 oql, oqh, okl, okh;
        #pragma unroll
        for (int i = 0; i < 8; ++i) {
            float ql = bf2f(qlo.u[i]), qh = bf2f(qhi.u[i]);
            float kl = bf2f(klo.u[i]), kh = bf2f(khi.u[i]);
            oql.u[i] = f2bf((ql * cc[i] - qh * ss[i]) * QSC);
            oqh.u[i] = f2bf((qh * cc[i] + ql * ss[i]) * QSC);
            okl.u[i] = f2bf(kl * cc[i] - kh * ss[i]);
            okh.u[i] = f2bf(kh * cc[i] + kl * ss[i]);
        }
        u16* qd = Qb + ((size_t)bh * Tt + t0 + row) * 64;
        u16* kd = Kb + ((size_t)bh * Tt + t0 + row) * 64;
        *(uint4*)&qd[d0]      = oql.v;
        *(uint4*)&qd[d0 + 32] = oqh.v;
        *(uint4*)&kd[d0]      = okl.v;
        *(uint4*)&kd[d0 + 32] = okh.v;
    }
    __syncthreads();

    {
        int d = t >> 2, kq = (t & 3) * 16;
        Frag8 a, b2;
        #pragma unroll
        for (int j = 0; j < 16; ++j) {
            int slot = kq + j;
            int key = ((slot >> 5) * 2 + ((slot >> 2) & 1)) * 16
                    + ((slot >> 3) & 3) * 4 + (slot & 3);
            u16 vv = Vs[key * 64 + d];
            if (j < 8) a.u[j] = vv; else b2.u[j - 8] = vv;
        }
        u16* vd = Vt + ((size_t)bh * 64 + d) * Tt + t0 + kq;
        *(uint4*)&vd[0] = a.v;
        *(uint4*)&vd[8] = b2.v;
    }
}

// ---------------------------------------------------------------------------
// MFMA flash attention v10: PAIRED q-tiles. Block = 4 waves, one (b,h),
// TWO q-tiles: heavy cH = 31-p and light cL = p (p = blockIdx>>5). The light
// tile's key range [0, cL*64+64) is a subset of the heavy's, so BOTH sets
// consume the same staged K/V tiles: staging+barriers -26%, all 512 blocks
// run exactly 32 iterations (perfect balance, 2 blocks/CU), and each wave
// carries two independent MFMA chains (ILP). Per-set machinery = v9
// (static-shift softmax, pi-permuted Vt, ones-MFMA l-sum, setprio).
// ---------------------------------------------------------------------------
__global__ __launch_bounds__(256) void attn_mfma_k(const u16* __restrict__ Qb,
                                                   const u16* __restrict__ Kb,
                                                   const u16* __restrict__ Vt,
                                                   u16* __restrict__ out) {
    const int i = blockIdx.x;           // 0..511
    const int p = i >> 5;               // 0..15
    const int bh = i & 31;
    const int cH = 31 - p, cL = p;      // cL < cH always
    const int b = bh >> 4, h = bh & 15;

    const int t = threadIdx.x;
    const int w = t >> 6;        // wave 0..3
    const int l = t & 63;
    const int q15 = l & 15;
    const int g2 = l >> 4;

    __shared__ __align__(16) u16 Ks[2][64 * 64];   // 16 KB
    __shared__ __align__(16) u16 VTs[2][64 * 64];  // 16 KB

    // ---- Q fragments for both q-sets ----
    Frag8 qf[2][2];
    #pragma unroll
    for (int s = 0; s < 2; ++s) {
        int qrow = (s ? cL : cH) * 64 + w * 16 + q15;
        const u16* qp = Qb + ((size_t)bh * Tt + qrow) * 64;
        qf[s][0] = *(const Frag8*)&qp[g2 * 8];
        qf[s][1] = *(const Frag8*)&qp[32 + g2 * 8];
    }

    Frag8 ones;
    #pragma unroll
    for (int e = 0; e < 8; ++e) ones.u[e] = 0x3F80;   // bf16 1.0

    f32x4 acco[2][4];
    #pragma unroll
    for (int s = 0; s < 2; ++s)
        #pragma unroll
        for (int dg = 0; dg < 4; ++dg) acco[s][dg] = (f32x4){0.f, 0.f, 0.f, 0.f};
    f32x4 acc_l[2] = {(f32x4){0.f, 0.f, 0.f, 0.f}, (f32x4){0.f, 0.f, 0.f, 0.f}};

    const int srow = l >> 3;      // 0..7
    const int cph = l & 7;
    const int xsw = cph ^ srow;   // staging chunk xor (rows ≡ srow mod 8)
    const u16* Kbase = Kb + (size_t)bh * Tt * 64;
    const u16* Vbase = Vt + (size_t)bh * 64 * Tt;

    // ---- prologue: stage tile 0 into buffer 0 ----
    #pragma unroll
    for (int iss = 0; iss < 2; ++iss) {
        int rr = w * 16 + iss * 8 + srow;
        gload_lds16(Kbase + (size_t)rr * 64 + xsw * 8, &Ks[0][(w * 16 + iss * 8) * 64]);
        gload_lds16(Vbase + (size_t)rr * Tt + xsw * 8, &VTs[0][(w * 16 + iss * 8) * 64]);
    }
    __syncthreads();

    int cur = 0;
    for (int j = 0; j <= cH; ++j) {
        // ---- issue next tile's staging (overlaps compute) ----
        if (j < cH) {
            #pragma unroll
            for (int iss = 0; iss < 2; ++iss) {
                int rr = w * 16 + iss * 8 + srow;
                gload_lds16(Kbase + (size_t)((j + 1) * 64 + rr) * 64 + xsw * 8,
                            &Ks[cur ^ 1][(w * 16 + iss * 8) * 64]);
                gload_lds16(Vbase + (size_t)rr * Tt + (j + 1) * 64 + xsw * 8,
                            &VTs[cur ^ 1][(w * 16 + iss * 8) * 64]);
            }
        }

        const u16* Kc = Ks[cur];
        const u16* Vc = VTs[cur];

        #pragma unroll
        for (int s = 0; s < 2; ++s) {
            if (s == 1 && j > cL) continue;     // light set done (block-uniform)
            const int cc = s ? cL : cH;

            // ---- QK^T (swapped): S^T[key][q], log2 domain ----
            f32x4 sacc[4];
            __builtin_amdgcn_s_setprio(1);
            #pragma unroll
            for (int g = 0; g < 4; ++g) {
                sacc[g] = (f32x4){0.f, 0.f, 0.f, 0.f};
                int krow = g * 16 + q15;
                #pragma unroll
                for (int kk = 0; kk < 2; ++kk) {
                    Frag8 kf = *(const Frag8*)&Kc[krow * 64 + (((kk * 4 + g2) ^ (krow & 7)) * 8)];
                    sacc[g] = __builtin_amdgcn_mfma_f32_16x16x32_bf16(
                        kf.b, qf[s][kk].b, sacc[g], 0, 0, 0);
                }
            }
            __builtin_amdgcn_s_setprio(0);
            if (j == cc) {   // diagonal tile: causal mask (true key order)
                #pragma unroll
                for (int g = 0; g < 4; ++g)
                    #pragma unroll
                    for (int r = 0; r < 4; ++r)
                        if (g * 16 + g2 * 4 + r > w * 16 + q15) sacc[g][r] = -1e30f;
            }

            // ---- P = exp2(S) straight into PV A-fragments (pi-Vt) ----
            Frag8 pa[2];
            #pragma unroll
            for (int kk = 0; kk < 2; ++kk)
                #pragma unroll
                for (int e = 0; e < 8; ++e)
                    pa[kk].b[e] = (__bf16)exp2f(sacc[2 * kk + (e >> 2)][e & 3]);

            // ---- l-sum + PV ----
            __builtin_amdgcn_s_setprio(1);
            acc_l[s] = __builtin_amdgcn_mfma_f32_16x16x32_bf16(pa[0].b, ones.b, acc_l[s], 0, 0, 0);
            acc_l[s] = __builtin_amdgcn_mfma_f32_16x16x32_bf16(pa[1].b, ones.b, acc_l[s], 0, 0, 0);
            #pragma unroll
            for (int dg = 0; dg < 4; ++dg) {
                int vrow = dg * 16 + q15;
                #pragma unroll
                for (int kk = 0; kk < 2; ++kk) {
                    Frag8 vf = *(const Frag8*)&Vc[vrow * 64 + (((kk * 4 + g2) ^ (vrow & 7)) * 8)];
                    acco[s][dg] = __builtin_amdgcn_mfma_f32_16x16x32_bf16(
                        pa[kk].b, vf.b, acco[s][dg], 0, 0, 0);
                }
            }
            __builtin_amdgcn_s_setprio(0);
        }

        // ---- single barrier per tile ----
        if (j < cH) __syncthreads();
        cur ^= 1;
    }

    // ---- epilogue: both sets; acc_l[s][r] is the row sum for row g2*4+r ----
    #pragma unroll
    for (int s = 0; s < 2; ++s) {
        float lr[4];
        #pragma unroll
        for (int r = 0; r < 4; ++r) lr[r] = 1.f / acc_l[s][r];
        const int qbase = (s ? cL : cH) * 64 + w * 16;
        #pragma unroll
        for (int dg = 0; dg < 4; ++dg)
            #pragma unroll
            for (int r = 0; r < 4; ++r)
                out[((size_t)(b * Tt + qbase + g2 * 4 + r)) * Cc + h * 64 + dg * 16 + q15] =
                    f2bf(acco[s][dg][r] * lr[r]);
    }
}

// ---------------------------------------------------------------------------
// Launch
// ---------------------------------------------------------------------------
extern "C" void kernel_launch(void* const* d_in, const int* in_sizes, int n_in,
                              void* d_out, int out_size, void* d_ws, size_t ws_size,
                              hipStream_t stream) {
    const float* x      = (const float*)d_in[0];
    const float* w_qkv  = (const float*)d_in[2];
    const float* b_qkv  = (const float*)d_in[3];
    const float* w_o    = (const float*)d_in[4];
    const float* b_o    = (const float*)d_in[5];
    const float* rms_w  = (const float*)d_in[6];
    float* out = (float*)d_out;

    char* ws = (char*)d_ws;
    u16*   xn_bf   = (u16*)ws;                                   // 8 MB [0,8)
    u16*   Kb      = (u16*)(ws + (size_t)(8 << 20));             // 8 MB [8,16)
    u16*   Vt      = (u16*)(ws + (size_t)(16 << 20));            // 8 MB [16,24)
    u16*   Qb      = (u16*)(ws + (size_t)(24 << 20));            // 8 MB [24,32)
    u16*   qkvb    = (u16*)(ws + (size_t)(32 << 20));            // 24 MB [32,56)
    u16*   wqkv_bf = (u16*)(ws + (size_t)(56 << 20));            // 6 MB [56,62)
    u16*   wo_bf   = (u16*)(ws + (size_t)(62 << 20));            // 2 MB [62,64)
    float* cosT    = (float*)(ws + (size_t)(64 << 20));          // 256 KB
    float* sinT    = (float*)(ws + (size_t)(64 << 20) + (1 << 18));
    u16*   attn_bf = xn_bf;   // xn dead after QKV GEMM

    prep_k<<<dim3(4352), dim3(256), 0, stream>>>(w_qkv, wqkv_bf, w_o, wo_bf,
                                                 cosT, sinT);
    rmsnorm_k<<<dim3(M_ROWS), dim3(256), 0, stream>>>(x, rms_w, xn_bf);
    gemm_mfma_k<true><<<dim3(3 * Cc / 128, M_ROWS / 128), dim3(256), 0, stream>>>(
        xn_bf, wqkv_bf, b_qkv, qkvb, M_ROWS, 3 * Cc, Cc);
    rope_pack_k<<<dim3(Tt / 64, Hh, Bb), dim3(256), 0, stream>>>(
        qkvb, cosT, sinT, Qb, Kb, Vt);
    attn_mfma_k<<<dim3(512), dim3(256), 0, stream>>>(Qb, Kb, Vt, attn_bf);
    gemm_mfma_k<false><<<dim3(Cc / 128, M_ROWS / 128), dim3(256), 0, stream>>>(
        attn_bf, wo_bf, b_o, out, M_ROWS, Cc, Cc);
}

// Round 18
// 127.108 us; speedup vs baseline: 1.0702x; 1.0327x over previous
//
#include <hip/hip_runtime.h>
#include <math.h>

// Problem constants: B=2, T=2048, C=1024, H=16, D=64
constexpr int Bb = 2;
constexpr int Tt = 2048;
constexpr int Cc = 1024;
constexpr int Hh = 16;
constexpr int M_ROWS = Bb * Tt;          // 4096
constexpr float EPSV = 1e-5f;

typedef __attribute__((ext_vector_type(4))) float f32x4;
typedef __attribute__((ext_vector_type(8))) __bf16 bf16x8;
using u16 = unsigned short;

union Frag8 {
    u16 u[8];
    unsigned int ui[4];
    uint4 v;
    bf16x8 b;
};

// fp32 -> bf16 round-to-nearest-even
__device__ __forceinline__ u16 f2bf(float f) {
    union { float f; unsigned int u; } c;
    c.f = f;
    unsigned int r = (c.u + 0x7fffu + ((c.u >> 16) & 1u)) >> 16;
    return (u16)r;
}
__device__ __forceinline__ float bf2f(u16 u) {
    union { unsigned int i; float f; } c;
    c.i = ((unsigned int)u) << 16;
    return c.f;
}

// async global->LDS, 16 B per lane; LDS dest = wave-uniform base + lane*16
__device__ __forceinline__ void gload_lds16(const void* g, void* l) {
    __builtin_amdgcn_global_load_lds(
        (__attribute__((address_space(1))) void*)const_cast<void*>(g),
        (__attribute__((address_space(3))) void*)l, 16, 0, 0);
}

// ---------------------------------------------------------------------------
// Prep (merged): weight bf16 converts + RoPE tables [T][32].
// Grid 4352 x 256: [0,3072) w_qkv, [3072,4096) w_o, [4096,4352) tables.
// ---------------------------------------------------------------------------
__global__ __launch_bounds__(256) void prep_k(const float* __restrict__ w_qkv,
                                              u16* __restrict__ wqkv_bf,
                                              const float* __restrict__ w_o,
                                              u16* __restrict__ wo_bf,
                                              float* __restrict__ cosT,
                                              float* __restrict__ sinT) {
    int blk = blockIdx.x;
    if (blk < 3072) {
        int i = (blk * 256 + threadIdx.x) * 4;
        float4 v = *(const float4*)&w_qkv[i];
        ushort4 o;
        o.x = f2bf(v.x); o.y = f2bf(v.y); o.z = f2bf(v.z); o.w = f2bf(v.w);
        *(ushort4*)&wqkv_bf[i] = o;
    } else if (blk < 4096) {
        int i = ((blk - 3072) * 256 + threadIdx.x) * 4;
        float4 v = *(const float4*)&w_o[i];
        ushort4 o;
        o.x = f2bf(v.x); o.y = f2bf(v.y); o.z = f2bf(v.z); o.w = f2bf(v.w);
        *(ushort4*)&wo_bf[i] = o;
    } else {
        int lin = (blk - 4096) * 256 + threadIdx.x;   // 0..65535 = t*32+j
        int tt = lin >> 5, j = lin & 31;
        float inv = exp2f(-(float)j * (log2f(10000.0f) / 32.0f));
        float a = (float)tt * inv;
        cosT[lin] = cosf(a);
        sinT[lin] = sinf(a);
    }
}

// ---------------------------------------------------------------------------
// RMSNorm: one block per row of C=1024; 256 threads x float4 -> bf16 out
// ---------------------------------------------------------------------------
__global__ __launch_bounds__(256) void rmsnorm_k(const float* __restrict__ x,
                                                 const float* __restrict__ w,
                                                 u16* __restrict__ xn) {
    int row = blockIdx.x;
    int tid = threadIdx.x;
    const float* xr = x + (size_t)row * Cc;
    float4 v = *(const float4*)&xr[tid * 4];
    float ss = v.x * v.x + v.y * v.y + v.z * v.z + v.w * v.w;
    #pragma unroll
    for (int off = 32; off > 0; off >>= 1) ss += __shfl_down(ss, off);
    __shared__ float ws_[4];
    if ((tid & 63) == 0) ws_[tid >> 6] = ss;
    __syncthreads();
    float tot = ws_[0] + ws_[1] + ws_[2] + ws_[3];
    float r = rsqrtf(tot * (1.0f / (float)Cc) + EPSV);
    float4 wv = *(const float4*)&w[tid * 4];
    ushort4 o;
    o.x = f2bf(v.x * r * wv.x);
    o.y = f2bf(v.y * r * wv.y);
    o.z = f2bf(v.z * r * wv.z);
    o.w = f2bf(v.w * r * wv.w);
    *(ushort4*)&xn[(size_t)row * Cc + tid * 4] = o;
}

// ---------------------------------------------------------------------------
// bf16 MFMA GEMM: O = A*W^T + bias. 128x128, BK=64, 4 waves. 2D grid
// (default decode is XCD/L2-friendly: gridDim.x % 8 == 0 at both shapes).
// ---------------------------------------------------------------------------
template<bool BF16OUT>
__global__ __launch_bounds__(256) void gemm_mfma_k(const u16* __restrict__ A,
                                                   const u16* __restrict__ W,
                                                   const float* __restrict__ bias,
                                                   void* __restrict__ Ov,
                                                   int M, int N, int K) {
    __shared__ __align__(16) u16 As[128 * 64];   // 16 KB
    __shared__ __align__(16) u16 Bs[128 * 64];   // 16 KB

    const int tid = threadIdx.x;
    const int w = tid >> 6;
    const int l = tid & 63;
    const int wr = w >> 1;
    const int wc = w & 1;
    const int q = l & 15;
    const int g = l >> 4;

    const int m0 = blockIdx.y * 128;
    const int n0 = blockIdx.x * 128;

    const int srow_in = l >> 3;
    const int p_chunk = l & 7;

    f32x4 acc[4][4];
    #pragma unroll
    for (int i = 0; i < 4; ++i)
        #pragma unroll
        for (int j = 0; j < 4; ++j)
            acc[i][j] = (f32x4){0.f, 0.f, 0.f, 0.f};

    const int nkt = K >> 6;
    for (int kt = 0; kt < nkt; ++kt) {
        const int k0 = kt << 6;
        __syncthreads();
        #pragma unroll
        for (int s = 0; s < 4; ++s) {
            int blk = s * 4 + w;
            int r = blk * 8 + srow_in;
            int c = p_chunk ^ (r & 7);
            gload_lds16(A + (size_t)(m0 + r) * K + k0 + c * 8, &As[blk * 512]);
            gload_lds16(W + (size_t)(n0 + r) * K + k0 + c * 8, &Bs[blk * 512]);
        }
        __syncthreads();

        #pragma unroll
        for (int kk = 0; kk < 2; ++kk) {
            Frag8 af[4], bf[4];
            const int ca = kk * 4 + g;
            #pragma unroll
            for (int i = 0; i < 4; ++i) {
                int ra = wr * 64 + i * 16 + q;
                af[i] = *(const Frag8*)&As[ra * 64 + ((ca ^ (ra & 7)) * 8)];
                int rb = wc * 64 + i * 16 + q;
                bf[i] = *(const Frag8*)&Bs[rb * 64 + ((ca ^ (rb & 7)) * 8)];
            }
            #pragma unroll
            for (int i = 0; i < 4; ++i)
                #pragma unroll
                for (int j = 0; j < 4; ++j)
                    acc[i][j] = __builtin_amdgcn_mfma_f32_16x16x32_bf16(
                        af[i].b, bf[j].b, acc[i][j], 0, 0, 0);
        }
    }

    #pragma unroll
    for (int i = 0; i < 4; ++i) {
        int row = m0 + wr * 64 + i * 16 + g * 4;
        #pragma unroll
        for (int j = 0; j < 4; ++j) {
            int col = n0 + wc * 64 + j * 16 + q;
            float bb = bias[col];
            #pragma unroll
            for (int r2 = 0; r2 < 4; ++r2) {
                float val = acc[i][j][r2] + bb;
                if (BF16OUT)
                    ((u16*)Ov)[(size_t)(row + r2) * N + col] = f2bf(val);
                else
                    ((float*)Ov)[(size_t)(row + r2) * N + col] = val;
            }
        }
    }
}

// ---------------------------------------------------------------------------
// RoPE + repack: qkv_bf16 [b,t,3,h,64] -> Qb/Kb [b,h,t,64] (Q pre-scaled by
// 0.125*log2e), Vt [b,h,64,T] with pi key permutation (zero-shuffle PV).
// ---------------------------------------------------------------------------
__global__ __launch_bounds__(256) void rope_pack_k(const u16* __restrict__ qkv,
                                                   const float* __restrict__ cosT,
                                                   const float* __restrict__ sinT,
                                                   u16* __restrict__ Qb,
                                                   u16* __restrict__ Kb,
                                                   u16* __restrict__ Vt) {
    const int t0 = blockIdx.x * 64;
    const int h = blockIdx.y, b = blockIdx.z;
    const int t = threadIdx.x;
    const int bh = b * Hh + h;
    __shared__ u16 Vs[64 * 64];
    constexpr float QSC = 0.125f * 1.44269504089f;   // 1/sqrt(D) * log2(e)

    {
        int row = t >> 2, d16 = (t & 3) * 16;
        const u16* vp = qkv + (size_t)(b * Tt + t0 + row) * 3072 + 2048 + h * 64 + d16;
        *(uint4*)&Vs[row * 64 + d16]     = *(const uint4*)vp;
        *(uint4*)&Vs[row * 64 + d16 + 8] = *(const uint4*)(vp + 8);
    }

    {
        int row = t >> 2, d0 = (t & 3) * 8;
        size_t rb = (size_t)(b * Tt + t0 + row) * 3072 + h * 64;
        const u16* qp = qkv + rb;
        const u16* kp = qkv + rb + 1024;
        Frag8 qlo, qhi, klo, khi;
        qlo.v = *(const uint4*)&qp[d0];
        qhi.v = *(const uint4*)&qp[d0 + 32];
        klo.v = *(const uint4*)&kp[d0];
        khi.v = *(const uint4*)&kp[d0 + 32];
        const float* cp = &cosT[(t0 + row) * 32 + d0];
        const float* sp = &sinT[(t0 + row) * 32 + d0];
        float4 c0 = *(const float4*)cp, c1 = *(const float4*)(cp + 4);
        float4 s0 = *(const float4*)sp, s1 = *(const float4*)(sp + 4);
        float cc[8] = {c0.x, c0.y, c0.z, c0.w, c1.x, c1.y, c1.z, c1.w};
        float ss[8] = {s0.x, s0.y, s0.z, s0.w, s1.x, s1.y, s1.z, s1.w};
        Frag8 oql, oqh, okl, okh;
        #pragma unroll
        for (int i = 0; i < 8; ++i) {
            float ql = bf2f(qlo.u[i]), qh = bf2f(qhi.u[i]);
            float kl = bf2f(klo.u[i]), kh = bf2f(khi.u[i]);
            oql.u[i] = f2bf((ql * cc[i] - qh * ss[i]) * QSC);
            oqh.u[i] = f2bf((qh * cc[i] + ql * ss[i]) * QSC);
            okl.u[i] = f2bf(kl * cc[i] - kh * ss[i]);
            okh.u[i] = f2bf(kh * cc[i] + kl * ss[i]);
        }
        u16* qd = Qb + ((size_t)bh * Tt + t0 + row) * 64;
        u16* kd = Kb + ((size_t)bh * Tt + t0 + row) * 64;
        *(uint4*)&qd[d0]      = oql.v;
        *(uint4*)&qd[d0 + 32] = oqh.v;
        *(uint4*)&kd[d0]      = okl.v;
        *(uint4*)&kd[d0 + 32] = okh.v;
    }
    __syncthreads();

    {
        int d = t >> 2, kq = (t & 3) * 16;
        Frag8 a, b2;
        #pragma unroll
        for (int j = 0; j < 16; ++j) {
            int slot = kq + j;
            int key = ((slot >> 5) * 2 + ((slot >> 2) & 1)) * 16
                    + ((slot >> 3) & 3) * 4 + (slot & 3);
            u16 vv = Vs[key * 64 + d];
            if (j < 8) a.u[j] = vv; else b2.u[j - 8] = vv;
        }
        u16* vd = Vt + ((size_t)bh * 64 + d) * Tt + t0 + kq;
        *(uint4*)&vd[0] = a.v;
        *(uint4*)&vd[8] = b2.v;
    }
}

// ---------------------------------------------------------------------------
// MFMA flash attention v11: paired q-tiles, 8 waves (512 thr).
// Waves 0-3 = heavy team (tile cH = 31-p), waves 4-7 = light team (cL = p).
// Both teams consume the SAME staged K/V tiles (staged once: each of the 8
// waves issues exactly 1 K + 1 V gload_lds per tile). Light team idles
// (staging+barrier only) once j > cL. 512 blocks x 8 waves = 16 waves/CU
// (2x R17's TLP) with R17's halved staging traffic. Per-set machinery = v9:
// static-shift softmax (no max tracking), pi-permuted Vt (zero-shuffle PV),
// ones-MFMA l-sum, setprio around MFMA clusters.
// ---------------------------------------------------------------------------
__global__ __launch_bounds__(512) void attn_mfma_k(const u16* __restrict__ Qb,
                                                   const u16* __restrict__ Kb,
                                                   const u16* __restrict__ Vt,
                                                   u16* __restrict__ out) {
    const int i = blockIdx.x;           // 0..511
    const int p = i >> 5;               // 0..15
    const int bh = i & 31;
    const int cH = 31 - p, cL = p;      // cL < cH always
    const int b = bh >> 4, h = bh & 15;

    const int t = threadIdx.x;
    const int w = t >> 6;        // wave 0..7
    const int team = w >> 2;     // 0 = heavy, 1 = light
    const int w4 = w & 3;        // row-group within team's tile
    const int l = t & 63;
    const int q15 = l & 15;
    const int g2 = l >> 4;

    __shared__ __align__(16) u16 Ks[2][64 * 64];   // 16 KB
    __shared__ __align__(16) u16 VTs[2][64 * 64];  // 16 KB

    const int cc = team ? cL : cH;     // this wave's q-tile

    // ---- Q fragments (exp2-domain scale pre-folded) ----
    Frag8 qf[2];
    {
        int qrow = cc * 64 + w4 * 16 + q15;
        const u16* qp = Qb + ((size_t)bh * Tt + qrow) * 64;
        qf[0] = *(const Frag8*)&qp[g2 * 8];
        qf[1] = *(const Frag8*)&qp[32 + g2 * 8];
    }

    Frag8 ones;
    #pragma unroll
    for (int e = 0; e < 8; ++e) ones.u[e] = 0x3F80;   // bf16 1.0

    f32x4 acco[4];
    #pragma unroll
    for (int dg = 0; dg < 4; ++dg) acco[dg] = (f32x4){0.f, 0.f, 0.f, 0.f};
    f32x4 acc_l = (f32x4){0.f, 0.f, 0.f, 0.f};

    // staging: wave w covers rows w*8 .. w*8+7 (srow = l>>3), chunk cph = l&7
    const int srow = l >> 3;
    const int cph = l & 7;
    const int xsw = cph ^ srow;        // rows ≡ srow (mod 8)
    const int rr = w * 8 + srow;
    const u16* Kbase = Kb + (size_t)bh * Tt * 64;
    const u16* Vbase = Vt + (size_t)bh * 64 * Tt;

    // ---- prologue: stage tile 0 into buffer 0 (1 K + 1 V issue per wave) ----
    gload_lds16(Kbase + (size_t)rr * 64 + xsw * 8, &Ks[0][(w * 8) * 64]);
    gload_lds16(Vbase + (size_t)rr * Tt + xsw * 8, &VTs[0][(w * 8) * 64]);
    __syncthreads();

    int cur = 0;
    for (int j = 0; j <= cH; ++j) {
        // ---- issue next tile's staging (overlaps compute) ----
        if (j < cH) {
            gload_lds16(Kbase + (size_t)((j + 1) * 64 + rr) * 64 + xsw * 8,
                        &Ks[cur ^ 1][(w * 8) * 64]);
            gload_lds16(Vbase + (size_t)rr * Tt + (j + 1) * 64 + xsw * 8,
                        &VTs[cur ^ 1][(w * 8) * 64]);
        }

        if (!(team == 1 && j > cL)) {   // light team done past its diagonal
            const u16* Kc = Ks[cur];
            const u16* Vc = VTs[cur];

            // ---- QK^T (swapped): S^T[key][q], log2 domain ----
            f32x4 sacc[4];
            __builtin_amdgcn_s_setprio(1);
            #pragma unroll
            for (int g = 0; g < 4; ++g) {
                sacc[g] = (f32x4){0.f, 0.f, 0.f, 0.f};
                int krow = g * 16 + q15;
                #pragma unroll
                for (int kk = 0; kk < 2; ++kk) {
                    Frag8 kf = *(const Frag8*)&Kc[krow * 64 + (((kk * 4 + g2) ^ (krow & 7)) * 8)];
                    sacc[g] = __builtin_amdgcn_mfma_f32_16x16x32_bf16(
                        kf.b, qf[kk].b, sacc[g], 0, 0, 0);
                }
            }
            __builtin_amdgcn_s_setprio(0);
            if (j == cc) {   // diagonal tile: causal mask (true key order)
                #pragma unroll
                for (int g = 0; g < 4; ++g)
                    #pragma unroll
                    for (int r = 0; r < 4; ++r)
                        if (g * 16 + g2 * 4 + r > w4 * 16 + q15) sacc[g][r] = -1e30f;
            }

            // ---- P = exp2(S) straight into PV A-fragments (pi-Vt) ----
            Frag8 pa[2];
            #pragma unroll
            for (int kk = 0; kk < 2; ++kk)
                #pragma unroll
                for (int e = 0; e < 8; ++e)
                    pa[kk].b[e] = (__bf16)exp2f(sacc[2 * kk + (e >> 2)][e & 3]);

            // ---- l-sum + PV ----
            __builtin_amdgcn_s_setprio(1);
            acc_l = __builtin_amdgcn_mfma_f32_16x16x32_bf16(pa[0].b, ones.b, acc_l, 0, 0, 0);
            acc_l = __builtin_amdgcn_mfma_f32_16x16x32_bf16(pa[1].b, ones.b, acc_l, 0, 0, 0);
            #pragma unroll
            for (int dg = 0; dg < 4; ++dg) {
                int vrow = dg * 16 + q15;
                #pragma unroll
                for (int kk = 0; kk < 2; ++kk) {
                    Frag8 vf = *(const Frag8*)&Vc[vrow * 64 + (((kk * 4 + g2) ^ (vrow & 7)) * 8)];
                    acco[dg] = __builtin_amdgcn_mfma_f32_16x16x32_bf16(
                        pa[kk].b, vf.b, acco[dg], 0, 0, 0);
                }
            }
            __builtin_amdgcn_s_setprio(0);
        }

        // ---- single barrier per tile ----
        if (j < cH) __syncthreads();
        cur ^= 1;
    }

    // ---- epilogue: acc_l[r] is the row sum for row g2*4+r ----
    float lr[4];
    #pragma unroll
    for (int r = 0; r < 4; ++r) lr[r] = 1.f / acc_l[r];
    const int qbase = cc * 64 + w4 * 16;
    #pragma unroll
    for (int dg = 0; dg < 4; ++dg)
        #pragma unroll
        for (int r = 0; r < 4; ++r)
            out[((size_t)(b * Tt + qbase + g2 * 4 + r)) * Cc + h * 64 + dg * 16 + q15] =
                f2bf(acco[dg][r] * lr[r]);
}

// ---------------------------------------------------------------------------
// Launch
// ---------------------------------------------------------------------------
extern "C" void kernel_launch(void* const* d_in, const int* in_sizes, int n_in,
                              void* d_out, int out_size, void* d_ws, size_t ws_size,
                              hipStream_t stream) {
    const float* x      = (const float*)d_in[0];
    const float* w_qkv  = (const float*)d_in[2];
    const float* b_qkv  = (const float*)d_in[3];
    const float* w_o    = (const float*)d_in[4];
    const float* b_o    = (const float*)d_in[5];
    const float* rms_w  = (const float*)d_in[6];
    float* out = (float*)d_out;

    char* ws = (char*)d_ws;
    u16*   xn_bf   = (u16*)ws;                                   // 8 MB [0,8)
    u16*   Kb      = (u16*)(ws + (size_t)(8 << 20));             // 8 MB [8,16)
    u16*   Vt      = (u16*)(ws + (size_t)(16 << 20));            // 8 MB [16,24)
    u16*   Qb      = (u16*)(ws + (size_t)(24 << 20));            // 8 MB [24,32)
    u16*   qkvb    = (u16*)(ws + (size_t)(32 << 20));            // 24 MB [32,56)
    u16*   wqkv_bf = (u16*)(ws + (size_t)(56 << 20));            // 6 MB [56,62)
    u16*   wo_bf   = (u16*)(ws + (size_t)(62 << 20));            // 2 MB [62,64)
    float* cosT    = (float*)(ws + (size_t)(64 << 20));          // 256 KB
    float* sinT    = (float*)(ws + (size_t)(64 << 20) + (1 << 18));
    u16*   attn_bf = xn_bf;   // xn dead after QKV GEMM

    prep_k<<<dim3(4352), dim3(256), 0, stream>>>(w_qkv, wqkv_bf, w_o, wo_bf,
                                                 cosT, sinT);
    rmsnorm_k<<<dim3(M_ROWS), dim3(256), 0, stream>>>(x, rms_w, xn_bf);
    gemm_mfma_k<true><<<dim3(3 * Cc / 128, M_ROWS / 128), dim3(256), 0, stream>>>(
        xn_bf, wqkv_bf, b_qkv, qkvb, M_ROWS, 3 * Cc, Cc);
    rope_pack_k<<<dim3(Tt / 64, Hh, Bb), dim3(256), 0, stream>>>(
        qkvb, cosT, sinT, Qb, Kb, Vt);
    attn_mfma_k<<<dim3(512), dim3(512), 0, stream>>>(Qb, Kb, Vt, attn_bf);
    gemm_mfma_k<false><<<dim3(Cc / 128, M_ROWS / 128), dim3(256), 0, stream>>>(
        attn_bf, wo_bf, b_o, out, M_ROWS, Cc, Cc);
}

// Round 19
// 117.452 us; speedup vs baseline: 1.1582x; 1.0822x over previous
//
#include <hip/hip_runtime.h>
#include <math.h>

// Problem constants: B=2, T=2048, C=1024, H=16, D=64
constexpr int Bb = 2;
constexpr int Tt = 2048;
constexpr int Cc = 1024;
constexpr int Hh = 16;
constexpr int M_ROWS = Bb * Tt;          // 4096
constexpr float EPSV = 1e-5f;

typedef __attribute__((ext_vector_type(4))) float f32x4;
typedef __attribute__((ext_vector_type(8))) __bf16 bf16x8;
using u16 = unsigned short;

union Frag8 {
    u16 u[8];
    unsigned int ui[4];
    uint4 v;
    bf16x8 b;
};

// fp32 -> bf16 round-to-nearest-even
__device__ __forceinline__ u16 f2bf(float f) {
    union { float f; unsigned int u; } c;
    c.f = f;
    unsigned int r = (c.u + 0x7fffu + ((c.u >> 16) & 1u)) >> 16;
    return (u16)r;
}
__device__ __forceinline__ float bf2f(u16 u) {
    union { unsigned int i; float f; } c;
    c.i = ((unsigned int)u) << 16;
    return c.f;
}

// async global->LDS, 16 B per lane; LDS dest = wave-uniform base + lane*16
__device__ __forceinline__ void gload_lds16(const void* g, void* l) {
    __builtin_amdgcn_global_load_lds(
        (__attribute__((address_space(1))) void*)const_cast<void*>(g),
        (__attribute__((address_space(3))) void*)l, 16, 0, 0);
}

// ---------------------------------------------------------------------------
// Prep (merged): weight bf16 converts + RoPE tables [T][32].
// Grid 4352 x 256: [0,3072) w_qkv, [3072,4096) w_o, [4096,4352) tables.
// ---------------------------------------------------------------------------
__global__ __launch_bounds__(256) void prep_k(const float* __restrict__ w_qkv,
                                              u16* __restrict__ wqkv_bf,
                                              const float* __restrict__ w_o,
                                              u16* __restrict__ wo_bf,
                                              float* __restrict__ cosT,
                                              float* __restrict__ sinT) {
    int blk = blockIdx.x;
    if (blk < 3072) {
        int i = (blk * 256 + threadIdx.x) * 4;
        float4 v = *(const float4*)&w_qkv[i];
        ushort4 o;
        o.x = f2bf(v.x); o.y = f2bf(v.y); o.z = f2bf(v.z); o.w = f2bf(v.w);
        *(ushort4*)&wqkv_bf[i] = o;
    } else if (blk < 4096) {
        int i = ((blk - 3072) * 256 + threadIdx.x) * 4;
        float4 v = *(const float4*)&w_o[i];
        ushort4 o;
        o.x = f2bf(v.x); o.y = f2bf(v.y); o.z = f2bf(v.z); o.w = f2bf(v.w);
        *(ushort4*)&wo_bf[i] = o;
    } else {
        int lin = (blk - 4096) * 256 + threadIdx.x;   // 0..65535 = t*32+j
        int tt = lin >> 5, j = lin & 31;
        float inv = exp2f(-(float)j * (log2f(10000.0f) / 32.0f));
        float a = (float)tt * inv;
        cosT[lin] = cosf(a);
        sinT[lin] = sinf(a);
    }
}

// ---------------------------------------------------------------------------
// RMSNorm: one block per row of C=1024; 256 threads x float4 -> bf16 out
// ---------------------------------------------------------------------------
__global__ __launch_bounds__(256) void rmsnorm_k(const float* __restrict__ x,
                                                 const float* __restrict__ w,
                                                 u16* __restrict__ xn) {
    int row = blockIdx.x;
    int tid = threadIdx.x;
    const float* xr = x + (size_t)row * Cc;
    float4 v = *(const float4*)&xr[tid * 4];
    float ss = v.x * v.x + v.y * v.y + v.z * v.z + v.w * v.w;
    #pragma unroll
    for (int off = 32; off > 0; off >>= 1) ss += __shfl_down(ss, off);
    __shared__ float ws_[4];
    if ((tid & 63) == 0) ws_[tid >> 6] = ss;
    __syncthreads();
    float tot = ws_[0] + ws_[1] + ws_[2] + ws_[3];
    float r = rsqrtf(tot * (1.0f / (float)Cc) + EPSV);
    float4 wv = *(const float4*)&w[tid * 4];
    ushort4 o;
    o.x = f2bf(v.x * r * wv.x);
    o.y = f2bf(v.y * r * wv.y);
    o.z = f2bf(v.z * r * wv.z);
    o.w = f2bf(v.w * r * wv.w);
    *(ushort4*)&xn[(size_t)row * Cc + tid * 4] = o;
}

// ---------------------------------------------------------------------------
// bf16 MFMA GEMM v2: 128x64 tile, BK=64, 4 waves (2 row-halves x 2 col-halves;
// wave computes 64x32). LDS 24KB -> 6 blocks/CU co-resident (vs 3 at 128x128)
// -- the GEMM was grid-limited latency-bound (R18: Occ 14%, MfmaUtil 20%).
// Same proven 2-barrier skeleton + source-chunk XOR swizzle (rule #21).
// ---------------------------------------------------------------------------
template<bool BF16OUT>
__global__ __launch_bounds__(256) void gemm_mfma_k(const u16* __restrict__ A,
                                                   const u16* __restrict__ W,
                                                   const float* __restrict__ bias,
                                                   void* __restrict__ Ov,
                                                   int M, int N, int K) {
    __shared__ __align__(16) u16 As[128 * 64];   // 16 KB
    __shared__ __align__(16) u16 Bs[64 * 64];    // 8 KB

    const int tid = threadIdx.x;
    const int w = tid >> 6;
    const int l = tid & 63;
    const int wr = w >> 1;           // row half (64 rows)
    const int wc = w & 1;            // col half (32 cols)
    const int q = l & 15;
    const int g = l >> 4;

    const int m0 = blockIdx.y * 128;
    const int n0 = blockIdx.x * 64;

    const int srow = l >> 3;         // 0..7
    const int cph = l & 7;
    const int cl = cph ^ srow;       // all staged rows ≡ srow (mod 8)

    f32x4 acc[4][2];
    #pragma unroll
    for (int i = 0; i < 4; ++i)
        #pragma unroll
        for (int j = 0; j < 2; ++j)
            acc[i][j] = (f32x4){0.f, 0.f, 0.f, 0.f};

    const int nkt = K >> 6;
    for (int kt = 0; kt < nkt; ++kt) {
        const int k0 = kt << 6;
        __syncthreads();
        // ---- stage A: 4 issues/wave (rows w*32 + iss*8 + srow) ----
        #pragma unroll
        for (int iss = 0; iss < 4; ++iss) {
            int r = w * 32 + iss * 8 + srow;
            gload_lds16(A + (size_t)(m0 + r) * K + k0 + cl * 8,
                        &As[(w * 32 + iss * 8) * 64]);
        }
        // ---- stage B: 2 issues/wave (rows w*16 + iss*8 + srow) ----
        #pragma unroll
        for (int iss = 0; iss < 2; ++iss) {
            int r = w * 16 + iss * 8 + srow;
            gload_lds16(W + (size_t)(n0 + r) * K + k0 + cl * 8,
                        &Bs[(w * 16 + iss * 8) * 64]);
        }
        __syncthreads();

        #pragma unroll
        for (int kk = 0; kk < 2; ++kk) {
            Frag8 af[4], bf[2];
            const int ca = kk * 4 + g;
            #pragma unroll
            for (int i = 0; i < 4; ++i) {
                int ra = wr * 64 + i * 16 + q;
                af[i] = *(const Frag8*)&As[ra * 64 + ((ca ^ (ra & 7)) * 8)];
            }
            #pragma unroll
            for (int j = 0; j < 2; ++j) {
                int rb = wc * 32 + j * 16 + q;
                bf[j] = *(const Frag8*)&Bs[rb * 64 + ((ca ^ (rb & 7)) * 8)];
            }
            #pragma unroll
            for (int i = 0; i < 4; ++i)
                #pragma unroll
                for (int j = 0; j < 2; ++j)
                    acc[i][j] = __builtin_amdgcn_mfma_f32_16x16x32_bf16(
                        af[i].b, bf[j].b, acc[i][j], 0, 0, 0);
        }
    }

    #pragma unroll
    for (int i = 0; i < 4; ++i) {
        int row = m0 + wr * 64 + i * 16 + g * 4;
        #pragma unroll
        for (int j = 0; j < 2; ++j) {
            int col = n0 + wc * 32 + j * 16 + q;
            float bb = bias[col];
            #pragma unroll
            for (int r2 = 0; r2 < 4; ++r2) {
                float val = acc[i][j][r2] + bb;
                if (BF16OUT)
                    ((u16*)Ov)[(size_t)(row + r2) * N + col] = f2bf(val);
                else
                    ((float*)Ov)[(size_t)(row + r2) * N + col] = val;
            }
        }
    }
}

// ---------------------------------------------------------------------------
// RoPE + repack: qkv_bf16 [b,t,3,h,64] -> Qb/Kb [b,h,t,64] (Q pre-scaled by
// 0.125*log2e), Vt [b,h,64,T] with pi key permutation (zero-shuffle PV).
// ---------------------------------------------------------------------------
__global__ __launch_bounds__(256) void rope_pack_k(const u16* __restrict__ qkv,
                                                   const float* __restrict__ cosT,
                                                   const float* __restrict__ sinT,
                                                   u16* __restrict__ Qb,
                                                   u16* __restrict__ Kb,
                                                   u16* __restrict__ Vt) {
    const int t0 = blockIdx.x * 64;
    const int h = blockIdx.y, b = blockIdx.z;
    const int t = threadIdx.x;
    const int bh = b * Hh + h;
    __shared__ u16 Vs[64 * 64];
    constexpr float QSC = 0.125f * 1.44269504089f;   // 1/sqrt(D) * log2(e)

    {
        int row = t >> 2, d16 = (t & 3) * 16;
        const u16* vp = qkv + (size_t)(b * Tt + t0 + row) * 3072 + 2048 + h * 64 + d16;
        *(uint4*)&Vs[row * 64 + d16]     = *(const uint4*)vp;
        *(uint4*)&Vs[row * 64 + d16 + 8] = *(const uint4*)(vp + 8);
    }

    {
        int row = t >> 2, d0 = (t & 3) * 8;
        size_t rb = (size_t)(b * Tt + t0 + row) * 3072 + h * 64;
        const u16* qp = qkv + rb;
        const u16* kp = qkv + rb + 1024;
        Frag8 qlo, qhi, klo, khi;
        qlo.v = *(const uint4*)&qp[d0];
        qhi.v = *(const uint4*)&qp[d0 + 32];
        klo.v = *(const uint4*)&kp[d0];
        khi.v = *(const uint4*)&kp[d0 + 32];
        const float* cp = &cosT[(t0 + row) * 32 + d0];
        const float* sp = &sinT[(t0 + row) * 32 + d0];
        float4 c0 = *(const float4*)cp, c1 = *(const float4*)(cp + 4);
        float4 s0 = *(const float4*)sp, s1 = *(const float4*)(sp + 4);
        float cc[8] = {c0.x, c0.y, c0.z, c0.w, c1.x, c1.y, c1.z, c1.w};
        float ss[8] = {s0.x, s0.y, s0.z, s0.w, s1.x, s1.y, s1.z, s1.w};
        Frag8 oql, oqh, okl, okh;
        #pragma unroll
        for (int i = 0; i < 8; ++i) {
            float ql = bf2f(qlo.u[i]), qh = bf2f(qhi.u[i]);
            float kl = bf2f(klo.u[i]), kh = bf2f(khi.u[i]);
            oql.u[i] = f2bf((ql * cc[i] - qh * ss[i]) * QSC);
            oqh.u[i] = f2bf((qh * cc[i] + ql * ss[i]) * QSC);
            okl.u[i] = f2bf(kl * cc[i] - kh * ss[i]);
            okh.u[i] = f2bf(kh * cc[i] + kl * ss[i]);
        }
        u16* qd = Qb + ((size_t)bh * Tt + t0 + row) * 64;
        u16* kd = Kb + ((size_t)bh * Tt + t0 + row) * 64;
        *(uint4*)&qd[d0]      = oql.v;
        *(uint4*)&qd[d0 + 32] = oqh.v;
        *(uint4*)&kd[d0]      = okl.v;
        *(uint4*)&kd[d0 + 32] = okh.v;
    }
    __syncthreads();

    {
        int d = t >> 2, kq = (t & 3) * 16;
        Frag8 a, b2;
        #pragma unroll
        for (int j = 0; j < 16; ++j) {
            int slot = kq + j;
            int key = ((slot >> 5) * 2 + ((slot >> 2) & 1)) * 16
                    + ((slot >> 3) & 3) * 4 + (slot & 3);
            u16 vv = Vs[key * 64 + d];
            if (j < 8) a.u[j] = vv; else b2.u[j - 8] = vv;
        }
        u16* vd = Vt + ((size_t)bh * 64 + d) * Tt + t0 + kq;
        *(uint4*)&vd[0] = a.v;
        *(uint4*)&vd[8] = b2.v;
    }
}

// ---------------------------------------------------------------------------
// MFMA flash attention v11 (unchanged R18 winner): paired q-tiles, 8 waves.
// Waves 0-3 = heavy team (cH = 31-p), waves 4-7 = light team (cL = p); both
// teams share the staged K/V tiles; static-shift softmax; pi-permuted Vt;
// ones-MFMA l-sum; setprio.
// ---------------------------------------------------------------------------
__global__ __launch_bounds__(512) void attn_mfma_k(const u16* __restrict__ Qb,
                                                   const u16* __restrict__ Kb,
                                                   const u16* __restrict__ Vt,
                                                   u16* __restrict__ out) {
    const int i = blockIdx.x;           // 0..511
    const int p = i >> 5;               // 0..15
    const int bh = i & 31;
    const int cH = 31 - p, cL = p;      // cL < cH always
    const int b = bh >> 4, h = bh & 15;

    const int t = threadIdx.x;
    const int w = t >> 6;        // wave 0..7
    const int team = w >> 2;     // 0 = heavy, 1 = light
    const int w4 = w & 3;        // row-group within team's tile
    const int l = t & 63;
    const int q15 = l & 15;
    const int g2 = l >> 4;

    __shared__ __align__(16) u16 Ks[2][64 * 64];   // 16 KB
    __shared__ __align__(16) u16 VTs[2][64 * 64];  // 16 KB

    const int cc = team ? cL : cH;     // this wave's q-tile

    Frag8 qf[2];
    {
        int qrow = cc * 64 + w4 * 16 + q15;
        const u16* qp = Qb + ((size_t)bh * Tt + qrow) * 64;
        qf[0] = *(const Frag8*)&qp[g2 * 8];
        qf[1] = *(const Frag8*)&qp[32 + g2 * 8];
    }

    Frag8 ones;
    #pragma unroll
    for (int e = 0; e < 8; ++e) ones.u[e] = 0x3F80;   // bf16 1.0

    f32x4 acco[4];
    #pragma unroll
    for (int dg = 0; dg < 4; ++dg) acco[dg] = (f32x4){0.f, 0.f, 0.f, 0.f};
    f32x4 acc_l = (f32x4){0.f, 0.f, 0.f, 0.f};

    const int srow = l >> 3;
    const int cph = l & 7;
    const int xsw = cph ^ srow;
    const int rr = w * 8 + srow;
    const u16* Kbase = Kb + (size_t)bh * Tt * 64;
    const u16* Vbase = Vt + (size_t)bh * 64 * Tt;

    gload_lds16(Kbase + (size_t)rr * 64 + xsw * 8, &Ks[0][(w * 8) * 64]);
    gload_lds16(Vbase + (size_t)rr * Tt + xsw * 8, &VTs[0][(w * 8) * 64]);
    __syncthreads();

    int cur = 0;
    for (int j = 0; j <= cH; ++j) {
        if (j < cH) {
            gload_lds16(Kbase + (size_t)((j + 1) * 64 + rr) * 64 + xsw * 8,
                        &Ks[cur ^ 1][(w * 8) * 64]);
            gload_lds16(Vbase + (size_t)rr * Tt + (j + 1) * 64 + xsw * 8,
                        &VTs[cur ^ 1][(w * 8) * 64]);
        }

        if (!(team == 1 && j > cL)) {
            const u16* Kc = Ks[cur];
            const u16* Vc = VTs[cur];

            f32x4 sacc[4];
            __builtin_amdgcn_s_setprio(1);
            #pragma unroll
            for (int g = 0; g < 4; ++g) {
                sacc[g] = (f32x4){0.f, 0.f, 0.f, 0.f};
                int krow = g * 16 + q15;
                #pragma unroll
                for (int kk = 0; kk < 2; ++kk) {
                    Frag8 kf = *(const Frag8*)&Kc[krow * 64 + (((kk * 4 + g2) ^ (krow & 7)) * 8)];
                    sacc[g] = __builtin_amdgcn_mfma_f32_16x16x32_bf16(
                        kf.b, qf[kk].b, sacc[g], 0, 0, 0);
                }
            }
            __builtin_amdgcn_s_setprio(0);
            if (j == cc) {
                #pragma unroll
                for (int g = 0; g < 4; ++g)
                    #pragma unroll
                    for (int r = 0; r < 4; ++r)
                        if (g * 16 + g2 * 4 + r > w4 * 16 + q15) sacc[g][r] = -1e30f;
            }

            Frag8 pa[2];
            #pragma unroll
            for (int kk = 0; kk < 2; ++kk)
                #pragma unroll
                for (int e = 0; e < 8; ++e)
                    pa[kk].b[e] = (__bf16)exp2f(sacc[2 * kk + (e >> 2)][e & 3]);

            __builtin_amdgcn_s_setprio(1);
            acc_l = __builtin_amdgcn_mfma_f32_16x16x32_bf16(pa[0].b, ones.b, acc_l, 0, 0, 0);
            acc_l = __builtin_amdgcn_mfma_f32_16x16x32_bf16(pa[1].b, ones.b, acc_l, 0, 0, 0);
            #pragma unroll
            for (int dg = 0; dg < 4; ++dg) {
                int vrow = dg * 16 + q15;
                #pragma unroll
                for (int kk = 0; kk < 2; ++kk) {
                    Frag8 vf = *(const Frag8*)&Vc[vrow * 64 + (((kk * 4 + g2) ^ (vrow & 7)) * 8)];
                    acco[dg] = __builtin_amdgcn_mfma_f32_16x16x32_bf16(
                        pa[kk].b, vf.b, acco[dg], 0, 0, 0);
                }
            }
            __builtin_amdgcn_s_setprio(0);
        }

        if (j < cH) __syncthreads();
        cur ^= 1;
    }

    float lr[4];
    #pragma unroll
    for (int r = 0; r < 4; ++r) lr[r] = 1.f / acc_l[r];
    const int qbase = cc * 64 + w4 * 16;
    #pragma unroll
    for (int dg = 0; dg < 4; ++dg)
        #pragma unroll
        for (int r = 0; r < 4; ++r)
            out[((size_t)(b * Tt + qbase + g2 * 4 + r)) * Cc + h * 64 + dg * 16 + q15] =
                f2bf(acco[dg][r] * lr[r]);
}

// ---------------------------------------------------------------------------
// Launch
// ---------------------------------------------------------------------------
extern "C" void kernel_launch(void* const* d_in, const int* in_sizes, int n_in,
                              void* d_out, int out_size, void* d_ws, size_t ws_size,
                              hipStream_t stream) {
    const float* x      = (const float*)d_in[0];
    const float* w_qkv  = (const float*)d_in[2];
    const float* b_qkv  = (const float*)d_in[3];
    const float* w_o    = (const float*)d_in[4];
    const float* b_o    = (const float*)d_in[5];
    const float* rms_w  = (const float*)d_in[6];
    float* out = (float*)d_out;

    char* ws = (char*)d_ws;
    u16*   xn_bf   = (u16*)ws;                                   // 8 MB [0,8)
    u16*   Kb      = (u16*)(ws + (size_t)(8 << 20));             // 8 MB [8,16)
    u16*   Vt      = (u16*)(ws + (size_t)(16 << 20));            // 8 MB [16,24)
    u16*   Qb      = (u16*)(ws + (size_t)(24 << 20));            // 8 MB [24,32)
    u16*   qkvb    = (u16*)(ws + (size_t)(32 << 20));            // 24 MB [32,56)
    u16*   wqkv_bf = (u16*)(ws + (size_t)(56 << 20));            // 6 MB [56,62)
    u16*   wo_bf   = (u16*)(ws + (size_t)(62 << 20));            // 2 MB [62,64)
    float* cosT    = (float*)(ws + (size_t)(64 << 20));          // 256 KB
    float* sinT    = (float*)(ws + (size_t)(64 << 20) + (1 << 18));
    u16*   attn_bf = xn_bf;   // xn dead after QKV GEMM

    prep_k<<<dim3(4352), dim3(256), 0, stream>>>(w_qkv, wqkv_bf, w_o, wo_bf,
                                                 cosT, sinT);
    rmsnorm_k<<<dim3(M_ROWS), dim3(256), 0, stream>>>(x, rms_w, xn_bf);
    gemm_mfma_k<true><<<dim3(3 * Cc / 64, M_ROWS / 128), dim3(256), 0, stream>>>(
        xn_bf, wqkv_bf, b_qkv, qkvb, M_ROWS, 3 * Cc, Cc);
    rope_pack_k<<<dim3(Tt / 64, Hh, Bb), dim3(256), 0, stream>>>(
        qkvb, cosT, sinT, Qb, Kb, Vt);
    attn_mfma_k<<<dim3(512), dim3(512), 0, stream>>>(Qb, Kb, Vt, attn_bf);
    gemm_mfma_k<false><<<dim3(Cc / 64, M_ROWS / 128), dim3(256), 0, stream>>>(
        attn_bf, wo_bf, b_o, out, M_ROWS, Cc, Cc);
}

// Round 20
// 113.668 us; speedup vs baseline: 1.1968x; 1.0333x over previous
//
#include <hip/hip_runtime.h>
#include <math.h>

// Problem constants: B=2, T=2048, C=1024, H=16, D=64
constexpr int Bb = 2;
constexpr int Tt = 2048;
constexpr int Cc = 1024;
constexpr int Hh = 16;
constexpr int M_ROWS = Bb * Tt;          // 4096
constexpr float EPSV = 1e-5f;

typedef __attribute__((ext_vector_type(4))) float f32x4;
typedef __attribute__((ext_vector_type(8))) __bf16 bf16x8;
using u16 = unsigned short;

union Frag8 {
    u16 u[8];
    unsigned int ui[4];
    uint4 v;
    bf16x8 b;
};

// fp32 -> bf16 round-to-nearest-even
__device__ __forceinline__ u16 f2bf(float f) {
    union { float f; unsigned int u; } c;
    c.f = f;
    unsigned int r = (c.u + 0x7fffu + ((c.u >> 16) & 1u)) >> 16;
    return (u16)r;
}
__device__ __forceinline__ float bf2f(u16 u) {
    union { unsigned int i; float f; } c;
    c.i = ((unsigned int)u) << 16;
    return c.f;
}

// async global->LDS, 16 B per lane; LDS dest = wave-uniform base + lane*16
__device__ __forceinline__ void gload_lds16(const void* g, void* l) {
    __builtin_amdgcn_global_load_lds(
        (__attribute__((address_space(1))) void*)const_cast<void*>(g),
        (__attribute__((address_space(3))) void*)l, 16, 0, 0);
}

// ---------------------------------------------------------------------------
// Prep (merged): weight bf16 converts + RoPE tables [T][32] + RMSNorm.
// Grid 8448 x 256: [0,3072) w_qkv, [3072,4096) w_o, [4096,4352) tables,
// [4352,8448) rmsnorm (one block per row).
// ---------------------------------------------------------------------------
__global__ __launch_bounds__(256) void prep_k(const float* __restrict__ w_qkv,
                                              u16* __restrict__ wqkv_bf,
                                              const float* __restrict__ w_o,
                                              u16* __restrict__ wo_bf,
                                              float* __restrict__ cosT,
                                              float* __restrict__ sinT,
                                              const float* __restrict__ x,
                                              const float* __restrict__ rms_w,
                                              u16* __restrict__ xn) {
    __shared__ float ws_[4];
    int blk = blockIdx.x;
    int tid = threadIdx.x;
    if (blk < 3072) {
        int i = (blk * 256 + tid) * 4;
        float4 v = *(const float4*)&w_qkv[i];
        ushort4 o;
        o.x = f2bf(v.x); o.y = f2bf(v.y); o.z = f2bf(v.z); o.w = f2bf(v.w);
        *(ushort4*)&wqkv_bf[i] = o;
    } else if (blk < 4096) {
        int i = ((blk - 3072) * 256 + tid) * 4;
        float4 v = *(const float4*)&w_o[i];
        ushort4 o;
        o.x = f2bf(v.x); o.y = f2bf(v.y); o.z = f2bf(v.z); o.w = f2bf(v.w);
        *(ushort4*)&wo_bf[i] = o;
    } else if (blk < 4352) {
        int lin = (blk - 4096) * 256 + tid;   // 0..65535 = t*32+j
        int tt = lin >> 5, j = lin & 31;
        float inv = exp2f(-(float)j * (log2f(10000.0f) / 32.0f));
        float a = (float)tt * inv;
        cosT[lin] = cosf(a);
        sinT[lin] = sinf(a);
    } else {
        int row = blk - 4352;
        const float* xr = x + (size_t)row * Cc;
        float4 v = *(const float4*)&xr[tid * 4];
        float ss = v.x * v.x + v.y * v.y + v.z * v.z + v.w * v.w;
        #pragma unroll
        for (int off = 32; off > 0; off >>= 1) ss += __shfl_down(ss, off);
        if ((tid & 63) == 0) ws_[tid >> 6] = ss;
        __syncthreads();
        float tot = ws_[0] + ws_[1] + ws_[2] + ws_[3];
        float r = rsqrtf(tot * (1.0f / (float)Cc) + EPSV);
        float4 wv = *(const float4*)&rms_w[tid * 4];
        ushort4 o;
        o.x = f2bf(v.x * r * wv.x);
        o.y = f2bf(v.y * r * wv.y);
        o.z = f2bf(v.z * r * wv.z);
        o.w = f2bf(v.w * r * wv.w);
        *(ushort4*)&xn[(size_t)row * Cc + tid * 4] = o;
    }
}

// ---------------------------------------------------------------------------
// bf16 MFMA GEMM v2 (R19 winner): 128x64 tile, BK=64, 4 waves, 24KB LDS ->
// 6 blocks/CU. 2-barrier skeleton + source-chunk XOR swizzle (rule #21).
// ---------------------------------------------------------------------------
template<bool BF16OUT>
__global__ __launch_bounds__(256) void gemm_mfma_k(const u16* __restrict__ A,
                                                   const u16* __restrict__ W,
                                                   const float* __restrict__ bias,
                                                   void* __restrict__ Ov,
                                                   int M, int N, int K) {
    __shared__ __align__(16) u16 As[128 * 64];   // 16 KB
    __shared__ __align__(16) u16 Bs[64 * 64];    // 8 KB

    const int tid = threadIdx.x;
    const int w = tid >> 6;
    const int l = tid & 63;
    const int wr = w >> 1;
    const int wc = w & 1;
    const int q = l & 15;
    const int g = l >> 4;

    const int m0 = blockIdx.y * 128;
    const int n0 = blockIdx.x * 64;

    const int srow = l >> 3;
    const int cph = l & 7;
    const int cl = cph ^ srow;

    f32x4 acc[4][2];
    #pragma unroll
    for (int i = 0; i < 4; ++i)
        #pragma unroll
        for (int j = 0; j < 2; ++j)
            acc[i][j] = (f32x4){0.f, 0.f, 0.f, 0.f};

    const int nkt = K >> 6;
    for (int kt = 0; kt < nkt; ++kt) {
        const int k0 = kt << 6;
        __syncthreads();
        #pragma unroll
        for (int iss = 0; iss < 4; ++iss) {
            int r = w * 32 + iss * 8 + srow;
            gload_lds16(A + (size_t)(m0 + r) * K + k0 + cl * 8,
                        &As[(w * 32 + iss * 8) * 64]);
        }
        #pragma unroll
        for (int iss = 0; iss < 2; ++iss) {
            int r = w * 16 + iss * 8 + srow;
            gload_lds16(W + (size_t)(n0 + r) * K + k0 + cl * 8,
                        &Bs[(w * 16 + iss * 8) * 64]);
        }
        __syncthreads();

        #pragma unroll
        for (int kk = 0; kk < 2; ++kk) {
            Frag8 af[4], bf[2];
            const int ca = kk * 4 + g;
            #pragma unroll
            for (int i = 0; i < 4; ++i) {
                int ra = wr * 64 + i * 16 + q;
                af[i] = *(const Frag8*)&As[ra * 64 + ((ca ^ (ra & 7)) * 8)];
            }
            #pragma unroll
            for (int j = 0; j < 2; ++j) {
                int rb = wc * 32 + j * 16 + q;
                bf[j] = *(const Frag8*)&Bs[rb * 64 + ((ca ^ (rb & 7)) * 8)];
            }
            #pragma unroll
            for (int i = 0; i < 4; ++i)
                #pragma unroll
                for (int j = 0; j < 2; ++j)
                    acc[i][j] = __builtin_amdgcn_mfma_f32_16x16x32_bf16(
                        af[i].b, bf[j].b, acc[i][j], 0, 0, 0);
        }
    }

    #pragma unroll
    for (int i = 0; i < 4; ++i) {
        int row = m0 + wr * 64 + i * 16 + g * 4;
        #pragma unroll
        for (int j = 0; j < 2; ++j) {
            int col = n0 + wc * 32 + j * 16 + q;
            float bb = bias[col];
            #pragma unroll
            for (int r2 = 0; r2 < 4; ++r2) {
                float val = acc[i][j][r2] + bb;
                if (BF16OUT)
                    ((u16*)Ov)[(size_t)(row + r2) * N + col] = f2bf(val);
                else
                    ((float*)Ov)[(size_t)(row + r2) * N + col] = val;
            }
        }
    }
}

// ---------------------------------------------------------------------------
// RoPE + repack: qkv_bf16 [b,t,3,h,64] -> Qb/Kb [b,h,t,64] (Q pre-scaled by
// 0.125*log2e), Vt [b,h,64,T] with pi key permutation (zero-shuffle PV).
// ---------------------------------------------------------------------------
__global__ __launch_bounds__(256) void rope_pack_k(const u16* __restrict__ qkv,
                                                   const float* __restrict__ cosT,
                                                   const float* __restrict__ sinT,
                                                   u16* __restrict__ Qb,
                                                   u16* __restrict__ Kb,
                                                   u16* __restrict__ Vt) {
    const int t0 = blockIdx.x * 64;
    const int h = blockIdx.y, b = blockIdx.z;
    const int t = threadIdx.x;
    const int bh = b * Hh + h;
    __shared__ u16 Vs[64 * 64];
    constexpr float QSC = 0.125f * 1.44269504089f;   // 1/sqrt(D) * log2(e)

    {
        int row = t >> 2, d16 = (t & 3) * 16;
        const u16* vp = qkv + (size_t)(b * Tt + t0 + row) * 3072 + 2048 + h * 64 + d16;
        *(uint4*)&Vs[row * 64 + d16]     = *(const uint4*)vp;
        *(uint4*)&Vs[row * 64 + d16 + 8] = *(const uint4*)(vp + 8);
    }

    {
        int row = t >> 2, d0 = (t & 3) * 8;
        size_t rb = (size_t)(b * Tt + t0 + row) * 3072 + h * 64;
        const u16* qp = qkv + rb;
        const u16* kp = qkv + rb + 1024;
        Frag8 qlo, qhi, klo, khi;
        qlo.v = *(const uint4*)&qp[d0];
        qhi.v = *(const uint4*)&qp[d0 + 32];
        klo.v = *(const uint4*)&kp[d0];
        khi.v = *(const uint4*)&kp[d0 + 32];
        const float* cp = &cosT[(t0 + row) * 32 + d0];
        const float* sp = &sinT[(t0 + row) * 32 + d0];
        float4 c0 = *(const float4*)cp, c1 = *(const float4*)(cp + 4);
        float4 s0 = *(const float4*)sp, s1 = *(const float4*)(sp + 4);
        float cc[8] = {c0.x, c0.y, c0.z, c0.w, c1.x, c1.y, c1.z, c1.w};
        float ss[8] = {s0.x, s0.y, s0.z, s0.w, s1.x, s1.y, s1.z, s1.w};
        Frag8 oql, oqh, okl, okh;
        #pragma unroll
        for (int i = 0; i < 8; ++i) {
            float ql = bf2f(qlo.u[i]), qh = bf2f(qhi.u[i]);
            float kl = bf2f(klo.u[i]), kh = bf2f(khi.u[i]);
            oql.u[i] = f2bf((ql * cc[i] - qh * ss[i]) * QSC);
            oqh.u[i] = f2bf((qh * cc[i] + ql * ss[i]) * QSC);
            okl.u[i] = f2bf(kl * cc[i] - kh * ss[i]);
            okh.u[i] = f2bf(kh * cc[i] + kl * ss[i]);
        }
        u16* qd = Qb + ((size_t)bh * Tt + t0 + row) * 64;
        u16* kd = Kb + ((size_t)bh * Tt + t0 + row) * 64;
        *(uint4*)&qd[d0]      = oql.v;
        *(uint4*)&qd[d0 + 32] = oqh.v;
        *(uint4*)&kd[d0]      = okl.v;
        *(uint4*)&kd[d0 + 32] = okh.v;
    }
    __syncthreads();

    {
        int d = t >> 2, kq = (t & 3) * 16;
        Frag8 a, b2;
        #pragma unroll
        for (int j = 0; j < 16; ++j) {
            int slot = kq + j;
            int key = ((slot >> 5) * 2 + ((slot >> 2) & 1)) * 16
                    + ((slot >> 3) & 3) * 4 + (slot & 3);
            u16 vv = Vs[key * 64 + d];
            if (j < 8) a.u[j] = vv; else b2.u[j - 8] = vv;
        }
        u16* vd = Vt + ((size_t)bh * 64 + d) * Tt + t0 + kq;
        *(uint4*)&vd[0] = a.v;
        *(uint4*)&vd[8] = b2.v;
    }
}

// ---------------------------------------------------------------------------
// MFMA flash attention v12: K-SPLIT teams. Static-shift softmax makes acco/
// acc_l pure sums over j -> the K-range splits freely. Block = 8 waves = 2
// teams x 4; ONE q-tile c per block; team0 does j in [0,h0), team1 [h0,nj).
// Both teams active every iteration (vs 52% in v11); per-team single-buffered
// staging (32KB LDS) -> 4 blocks/CU = 32 waves/CU static. Cross-team partial
// reduction through LDS at the end. Grid 1024 heavy-first.
// ---------------------------------------------------------------------------
__global__ __launch_bounds__(512) void attn_mfma_k(const u16* __restrict__ Qb,
                                                   const u16* __restrict__ Kb,
                                                   const u16* __restrict__ Vt,
                                                   u16* __restrict__ out) {
    const int i = blockIdx.x;           // 0..1023
    int c, bh;
    if (i < 512) { c = 31 - (i >> 5); bh = i & 31; }        // heavy first
    else         { int k = i - 512; c = k >> 5; bh = k & 31; }
    const int b = bh >> 4, h = bh & 15;

    const int t = threadIdx.x;
    const int w = t >> 6;        // wave 0..7
    const int team = w >> 2;
    const int w4 = w & 3;
    const int l = t & 63;
    const int q15 = l & 15;
    const int g2 = l >> 4;

    __shared__ __align__(16) char lds[32768];
    u16* Ksm = (u16*)(lds + team * 8192);            // [64][64] this team's K
    u16* Vsm = (u16*)(lds + 16384 + team * 8192);    // [64][64] this team's V^T
    float* red = (float*)lds;                        // reduction (20 KB), reused

    const int nj = c + 1;
    const int h0 = (nj + 1) >> 1;
    const int myn = team ? (nj - h0) : h0;
    const int jbase = team ? h0 : 0;

    // ---- Q fragments (exp2-domain scale pre-folded); same q-tile, both teams
    Frag8 qf[2];
    {
        int qrow = c * 64 + w4 * 16 + q15;
        const u16* qp = Qb + ((size_t)bh * Tt + qrow) * 64;
        qf[0] = *(const Frag8*)&qp[g2 * 8];
        qf[1] = *(const Frag8*)&qp[32 + g2 * 8];
    }

    Frag8 ones;
    #pragma unroll
    for (int e = 0; e < 8; ++e) ones.u[e] = 0x3F80;   // bf16 1.0

    f32x4 acco[4];
    #pragma unroll
    for (int dg = 0; dg < 4; ++dg) acco[dg] = (f32x4){0.f, 0.f, 0.f, 0.f};
    f32x4 acc_l = (f32x4){0.f, 0.f, 0.f, 0.f};

    const int srow = l >> 3;
    const int cph = l & 7;
    const int xsw = cph ^ srow;
    const u16* Kbase = Kb + (size_t)bh * Tt * 64;
    const u16* Vbase = Vt + (size_t)bh * 64 * Tt;

    for (int it = 0; it < h0; ++it) {
        __syncthreads();                 // prior compute done (both teams)
        const int j = jbase + it;
        if (it < myn) {
            // ---- stage this team's tile j (single buffer) ----
            #pragma unroll
            for (int iss = 0; iss < 2; ++iss) {
                int rr = w4 * 16 + iss * 8 + srow;
                gload_lds16(Kbase + (size_t)(j * 64 + rr) * 64 + xsw * 8,
                            &Ksm[(w4 * 16 + iss * 8) * 64]);
                gload_lds16(Vbase + (size_t)rr * Tt + j * 64 + xsw * 8,
                            &Vsm[(w4 * 16 + iss * 8) * 64]);
            }
        }
        __syncthreads();                 // staged (vmcnt drained at barrier)
        if (it < myn) {
            // ---- QK^T (swapped): S^T[key][q], log2 domain ----
            f32x4 sacc[4];
            __builtin_amdgcn_s_setprio(1);
            #pragma unroll
            for (int g = 0; g < 4; ++g) {
                sacc[g] = (f32x4){0.f, 0.f, 0.f, 0.f};
                int krow = g * 16 + q15;
                #pragma unroll
                for (int kk = 0; kk < 2; ++kk) {
                    Frag8 kf = *(const Frag8*)&Ksm[krow * 64 + (((kk * 4 + g2) ^ (krow & 7)) * 8)];
                    sacc[g] = __builtin_amdgcn_mfma_f32_16x16x32_bf16(
                        kf.b, qf[kk].b, sacc[g], 0, 0, 0);
                }
            }
            __builtin_amdgcn_s_setprio(0);
            if (j == c) {   // diagonal tile: causal mask (true key order)
                #pragma unroll
                for (int g = 0; g < 4; ++g)
                    #pragma unroll
                    for (int r = 0; r < 4; ++r)
                        if (g * 16 + g2 * 4 + r > w4 * 16 + q15) sacc[g][r] = -1e30f;
            }

            // ---- P = exp2(S) straight into PV A-fragments (pi-Vt) ----
            Frag8 pa[2];
            #pragma unroll
            for (int kk = 0; kk < 2; ++kk)
                #pragma unroll
                for (int e = 0; e < 8; ++e)
                    pa[kk].b[e] = (__bf16)exp2f(sacc[2 * kk + (e >> 2)][e & 3]);

            // ---- l-sum + PV ----
            __builtin_amdgcn_s_setprio(1);
            acc_l = __builtin_amdgcn_mfma_f32_16x16x32_bf16(pa[0].b, ones.b, acc_l, 0, 0, 0);
            acc_l = __builtin_amdgcn_mfma_f32_16x16x32_bf16(pa[1].b, ones.b, acc_l, 0, 0, 0);
            #pragma unroll
            for (int dg = 0; dg < 4; ++dg) {
                int vrow = dg * 16 + q15;
                #pragma unroll
                for (int kk = 0; kk < 2; ++kk) {
                    Frag8 vf = *(const Frag8*)&Vsm[vrow * 64 + (((kk * 4 + g2) ^ (vrow & 7)) * 8)];
                    acco[dg] = __builtin_amdgcn_mfma_f32_16x16x32_bf16(
                        pa[kk].b, vf.b, acco[dg], 0, 0, 0);
                }
            }
            __builtin_amdgcn_s_setprio(0);
        }
    }

    // ---- cross-team reduction: team1 -> LDS, team0 adds + epilogue ----
    __syncthreads();
    const int slot = (w4 * 64 + l) * 20;
    if (team == 1) {
        #pragma unroll
        for (int dg = 0; dg < 4; ++dg)
            #pragma unroll
            for (int r = 0; r < 4; ++r) red[slot + dg * 4 + r] = acco[dg][r];
        #pragma unroll
        for (int r = 0; r < 4; ++r) red[slot + 16 + r] = acc_l[r];
    }
    __syncthreads();
    if (team == 0) {
        #pragma unroll
        for (int dg = 0; dg < 4; ++dg)
            #pragma unroll
            for (int r = 0; r < 4; ++r) acco[dg][r] += red[slot + dg * 4 + r];
        #pragma unroll
        for (int r = 0; r < 4; ++r) acc_l[r] += red[slot + 16 + r];

        float lr[4];
        #pragma unroll
        for (int r = 0; r < 4; ++r) lr[r] = 1.f / acc_l[r];
        const int qbase = c * 64 + w4 * 16;
        #pragma unroll
        for (int dg = 0; dg < 4; ++dg)
            #pragma unroll
            for (int r = 0; r < 4; ++r)
                out[((size_t)(b * Tt + qbase + g2 * 4 + r)) * Cc + h * 64 + dg * 16 + q15] =
                    f2bf(acco[dg][r] * lr[r]);
    }
}

// ---------------------------------------------------------------------------
// Launch
// ---------------------------------------------------------------------------
extern "C" void kernel_launch(void* const* d_in, const int* in_sizes, int n_in,
                              void* d_out, int out_size, void* d_ws, size_t ws_size,
                              hipStream_t stream) {
    const float* x      = (const float*)d_in[0];
    const float* w_qkv  = (const float*)d_in[2];
    const float* b_qkv  = (const float*)d_in[3];
    const float* w_o    = (const float*)d_in[4];
    const float* b_o    = (const float*)d_in[5];
    const float* rms_w  = (const float*)d_in[6];
    float* out = (float*)d_out;

    char* ws = (char*)d_ws;
    u16*   xn_bf   = (u16*)ws;                                   // 8 MB [0,8)
    u16*   Kb      = (u16*)(ws + (size_t)(8 << 20));             // 8 MB [8,16)
    u16*   Vt      = (u16*)(ws + (size_t)(16 << 20));            // 8 MB [16,24)
    u16*   Qb      = (u16*)(ws + (size_t)(24 << 20));            // 8 MB [24,32)
    u16*   qkvb    = (u16*)(ws + (size_t)(32 << 20));            // 24 MB [32,56)
    u16*   wqkv_bf = (u16*)(ws + (size_t)(56 << 20));            // 6 MB [56,62)
    u16*   wo_bf   = (u16*)(ws + (size_t)(62 << 20));            // 2 MB [62,64)
    float* cosT    = (float*)(ws + (size_t)(64 << 20));          // 256 KB
    float* sinT    = (float*)(ws + (size_t)(64 << 20) + (1 << 18));
    u16*   attn_bf = xn_bf;   // xn dead after QKV GEMM

    prep_k<<<dim3(8448), dim3(256), 0, stream>>>(w_qkv, wqkv_bf, w_o, wo_bf,
                                                 cosT, sinT, x, rms_w, xn_bf);
    gemm_mfma_k<true><<<dim3(3 * Cc / 64, M_ROWS / 128), dim3(256), 0, stream>>>(
        xn_bf, wqkv_bf, b_qkv, qkvb, M_ROWS, 3 * Cc, Cc);
    rope_pack_k<<<dim3(Tt / 64, Hh, Bb), dim3(256), 0, stream>>>(
        qkvb, cosT, sinT, Qb, Kb, Vt);
    attn_mfma_k<<<dim3(1024), dim3(512), 0, stream>>>(Qb, Kb, Vt, attn_bf);
    gemm_mfma_k<false><<<dim3(Cc / 64, M_ROWS / 128), dim3(256), 0, stream>>>(
        attn_bf, wo_bf, b_o, out, M_ROWS, Cc, Cc);
}